// Round 9
// baseline (36.350 us; speedup 1.0000x reference)
//
#include <hip/hip_runtime.h>
#include <math.h>

#define N_PTS 32768
#define LL    2048

// d_ws dword/float offsets
#define KT_U      0          // uint: [2][2048][2] K frag table {k0k1, k2_0}
#define VT_U      8192       // uint: [2][4][1024] V planes (v0,v1,v2,ones) f16-pairs
#define PART_OFF  16384      // float [1024][12] BN partials
#define MS_OFF    28672      // [6][2]  {m, expsum}
#define W_OFF     28684      // [6][6]  exp-weighted sums
#define CS_OFF    28720      // [3][6]  colsum batch0
#define PBKM_OFF  28738      // [8][3]  per-kvblock |k| max
#define BNS_OFF   28762      // [6]
#define BNB_OFF   28768      // [6]

typedef __fp16 h2    __attribute__((ext_vector_type(2)));
typedef __fp16 f16x4 __attribute__((ext_vector_type(4)));
typedef float  f32x4 __attribute__((ext_vector_type(4)));

__device__ __forceinline__ unsigned h2_bits(h2 h){
  union { h2 h; unsigned u; } x; x.h = h; return x.u;
}
__device__ __forceinline__ float wave_reduce_sum(float v){
  #pragma unroll
  for (int off = 32; off; off >>= 1) v += __shfl_xor(v, off, 64);
  return v;
}
__device__ __forceinline__ float wave_reduce_max(float v){
  #pragma unroll
  for (int off = 32; off; off >>= 1) v = fmaxf(v, __shfl_xor(v, off, 64));
  return v;
}

// ---------------------------------------------------------------- prep ----
// 14 blocks x 256. Blocks 0-5: per-(b,nc) global stats (max, expsum, W, CS).
// Blocks 6-13: kv table build; per-block |k| max into PBKM slots.
__global__ __launch_bounds__(256)
void prep_kernel(const float* __restrict__ curves, const float* __restrict__ Watt,
                 const float* __restrict__ Wb,  const float* __restrict__ Wbv,
                 const float* __restrict__ Wpn, const float* __restrict__ bpn,
                 float* __restrict__ ws)
{
  const int blk = blockIdx.x, tid = threadIdx.x;
  const int lane = tid & 63, wid = tid >> 6;
  __shared__ float sred[4 * 13];
  __shared__ float msh;

  float watt[6];
  #pragma unroll
  for (int c = 0; c < 6; c++) watt[c] = Watt[c];

  if (blk < 6) {
    const int b = blk / 3, nc = blk % 3;
    const float* cb = curves + b * 18 * LL;
    float av[8], pm = -1e30f;
    #pragma unroll
    for (int k = 0; k < 8; k++) {
      const int l = tid + k * 256;
      float s = 0.f;
      #pragma unroll
      for (int c = 0; c < 6; c++) s = fmaf(cb[(c * 3 + nc) * LL + l], watt[c], s);
      av[k] = s; pm = fmaxf(pm, s);
    }
    pm = wave_reduce_max(pm);
    if (lane == 0) sred[wid] = pm;
    __syncthreads();
    if (tid == 0) msh = fmaxf(fmaxf(sred[0], sred[1]), fmaxf(sred[2], sred[3]));
    __syncthreads();
    const float m = msh;

    float vals[13];
    #pragma unroll
    for (int j = 0; j < 13; j++) vals[j] = 0.f;
    #pragma unroll
    for (int k = 0; k < 8; k++) {
      const int l = tid + k * 256;
      float e = __expf(av[k] - m);
      vals[0] += e;
      #pragma unroll
      for (int c = 0; c < 6; c++) {
        float v = cb[(c * 3 + nc) * LL + l];
        vals[1 + c] = fmaf(v, e, vals[1 + c]);
        if (b == 0) vals[7 + c] += v;
      }
    }
    __syncthreads();
    #pragma unroll
    for (int j = 0; j < 13; j++) vals[j] = wave_reduce_sum(vals[j]);
    if (lane == 0) { for (int j = 0; j < 13; j++) sred[wid * 13 + j] = vals[j]; }
    __syncthreads();
    if (tid == 0) {
      ws[MS_OFF + blk * 2] = m;
      for (int j = 0; j < 13; j++) {
        float s = sred[j] + sred[13 + j] + sred[26 + j] + sred[39 + j];
        if (j == 0) ws[MS_OFF + blk * 2 + 1] = s;
        else if (j < 7) ws[W_OFF + blk * 6 + (j - 1)] = s;
        else if (b == 0) ws[CS_OFF + nc * 6 + (j - 7)] = s;
      }
    }
  } else {
    const int idx = (blk - 6) * 256 + tid;   // 0..2047
    const int b = idx >> 10, pp = idx & 1023, l = pp * 2;
    const float* cb = curves + b * 18 * LL;

    float2 cv[6][3], pv[6][3];
    #pragma unroll
    for (int c = 0; c < 6; c++)
      #pragma unroll
      for (int nc = 0; nc < 3; nc++) {
        cv[c][nc] = *(const float2*)&cb[(c * 3 + nc) * LL + l];
        pv[c][nc] = *(const float2*)&curves[(c * 3 + nc) * LL + l];  // batch 0
      }
    float a[3][2];
    #pragma unroll
    for (int nc = 0; nc < 3; nc++) {
      float sx = 0.f, sy = 0.f;
      #pragma unroll
      for (int c = 0; c < 6; c++) {
        sx = fmaf(cv[c][nc].x, watt[c], sx);
        sy = fmaf(cv[c][nc].y, watt[c], sy);
      }
      a[nc][0] = sx; a[nc][1] = sy;
    }

    float wb_r[18], wbv_r[18];
    #pragma unroll
    for (int i = 0; i < 18; i++) { wb_r[i] = Wb[i]; wbv_r[i] = Wbv[i]; }
    const float wn0 = (Wpn[0] + Wpn[3] + Wpn[6]) * (1.f / 3.f);
    const float wn1 = (Wpn[1] + Wpn[4] + Wpn[7]) * (1.f / 3.f);
    const float wn2 = (Wpn[2] + Wpn[5] + Wpn[8]) * (1.f / 3.f);
    const float bnb = (bpn[0] + bpn[1] + bpn[2]) * (1.f / 3.f);

    float kk[2][3], vv[2][3], km[3] = {0.f, 0.f, 0.f};
    #pragma unroll
    for (int e = 0; e < 2; e++) {
      float a0 = a[0][e], a1 = a[1][e], a2 = a[2][e];
      float mm = fmaxf(fmaxf(a0, a1), a2);
      float e0 = __expf(a0 - mm), e1 = __expf(a1 - mm), e2 = __expf(a2 - mm);
      float r = 1.f / (e0 + e1 + e2);
      float ga[6];
      #pragma unroll
      for (int c = 0; c < 6; c++) {
        float c0 = e ? cv[c][0].y : cv[c][0].x;
        float c1 = e ? cv[c][1].y : cv[c][1].x;
        float c2 = e ? cv[c][2].y : cv[c][2].x;
        float p0 = e ? pv[c][0].y : pv[c][0].x;
        float p1 = e ? pv[c][1].y : pv[c][1].x;
        float p2 = e ? pv[c][2].y : pv[c][2].x;
        float intra = (c0 * e0 + c1 * e1 + c2 * e2) * r;
        float pn = p0 * wn0 + p1 * wn1 + p2 * wn2 + bnb;
        ga[c] = intra + pn;
      }
      float k0 = 0, k1 = 0, k2 = 0, v0 = 0, v1 = 0, v2 = 0;
      #pragma unroll
      for (int c = 0; c < 6; c++) {
        k0 += wb_r[c] * ga[c];  k1 += wb_r[6 + c] * ga[c];  k2 += wb_r[12 + c] * ga[c];
        v0 += wbv_r[c] * ga[c]; v1 += wbv_r[6 + c] * ga[c]; v2 += wbv_r[12 + c] * ga[c];
      }
      kk[e][0] = k0; kk[e][1] = k1; kk[e][2] = k2;
      vv[e][0] = v0; vv[e][1] = v1; vv[e][2] = v2;
      km[0] = fmaxf(km[0], fabsf(k0));
      km[1] = fmaxf(km[1], fabsf(k1));
      km[2] = fmaxf(km[2], fabsf(k2));
    }
    unsigned* ktg = (unsigned*)ws + KT_U + b * 4096;
    ktg[4 * pp + 0] = h2_bits(__builtin_amdgcn_cvt_pkrtz(kk[0][0], kk[0][1]));
    ktg[4 * pp + 1] = h2_bits(__builtin_amdgcn_cvt_pkrtz(kk[0][2], 0.f));
    ktg[4 * pp + 2] = h2_bits(__builtin_amdgcn_cvt_pkrtz(kk[1][0], kk[1][1]));
    ktg[4 * pp + 3] = h2_bits(__builtin_amdgcn_cvt_pkrtz(kk[1][2], 0.f));
    unsigned* vtg = (unsigned*)ws + VT_U + b * 4096;
    vtg[0 * 1024 + pp] = h2_bits(__builtin_amdgcn_cvt_pkrtz(vv[0][0], vv[1][0]));
    vtg[1 * 1024 + pp] = h2_bits(__builtin_amdgcn_cvt_pkrtz(vv[0][1], vv[1][1]));
    vtg[2 * 1024 + pp] = h2_bits(__builtin_amdgcn_cvt_pkrtz(vv[0][2], vv[1][2]));
    vtg[3 * 1024 + pp] = h2_bits(__builtin_amdgcn_cvt_pkrtz(1.f, 1.f));

    #pragma unroll
    for (int j = 0; j < 3; j++) km[j] = wave_reduce_max(km[j]);
    if (lane == 0) { for (int j = 0; j < 3; j++) sred[wid * 3 + j] = km[j]; }
    __syncthreads();
    if (tid == 0) {
      for (int j = 0; j < 3; j++)
        ws[PBKM_OFF + (blk - 6) * 3 + j] =
          fmaxf(fmaxf(sred[j], sred[3 + j]), fmaxf(sred[6 + j], sred[9 + j]));
    }
  }
}

// ---------------------------------------------------------------- main ----
// 1024 blocks x 256 thr (4 waves). Block = 64 rows = 4 row-tiles of 16.
// Wave w = key-quarter kq (32 chunks of 16 keys), processes ALL 4 row-tiles:
// per chunk one K-read + one V-read feed 4 score MFMAs + 4 PV MFMAs (dual
// accumulators -> 8 independent chains). Quarters combined via LDS cross.
__global__ __launch_bounds__(256, 4)
void attn_kernel(const float* __restrict__ x,  const float* __restrict__ Wc,
                 const float* __restrict__ Wd, const float* __restrict__ lng,
                 const float* __restrict__ lnb,
                 const float* __restrict__ Wa, const float* __restrict__ Wav,
                 const float* __restrict__ Wpl, const float* __restrict__ bpl,
                 float* __restrict__ ws, float* __restrict__ yout)
{
  __shared__ __align__(16) unsigned kt[4224];  // 2048 keys x 2 dw; zeros @4096-97
  __shared__ __align__(16) unsigned vt[4224];  // 4 planes x 1028; zeros @4112-13
  __shared__ float4 cross[4][64];
  __shared__ float gis[18], kis[9], vis[9];
  const int tid  = threadIdx.x, blk = blockIdx.x;
  const int lane = tid & 63, kq = tid >> 6;
  const int col  = lane & 15, hi4 = lane >> 4;
  const int rbase = blk * 64;
  const int b    = rbase >> 15;
  const int nb   = rbase & (N_PTS - 1);

  // ---- stage K/V tables ----
  {
    const uint4* ktg = (const uint4*)((const unsigned*)ws + KT_U + b * 4096);
    uint4* kt4 = (uint4*)kt;
    for (int i = tid; i < 1024; i += 256) kt4[i] = ktg[i];
    const uint2* vtg2 = (const uint2*)((const unsigned*)ws + VT_U + b * 4096);
    for (int i = tid; i < 2048; i += 256) {
      int pl = i >> 9, off = (i & 511) << 1;
      *(uint2*)&vt[pl * 1028 + off] = vtg2[i];
    }
    if (tid < 2) { kt[4096 + tid] = 0; vt[4112 + tid] = 0; }
  }
  // gis by lanes 0-17 (overlaps staging)
  if (tid < 18) {
    int c = tid / 3, m = tid % 3;
    float pl_ = bpl[m];
    #pragma unroll
    for (int k = 0; k < 3; k++)
      pl_ = fmaf(Wpl[m * 3 + k], ws[CS_OFF + k * 6 + c] * (1.f / LL), pl_);
    gis[c * 3 + m] = ws[W_OFF + (b * 3 + m) * 6 + c] / ws[MS_OFF + (b * 3 + m) * 2 + 1] + pl_;
  }
  __syncthreads();
  if (tid < 9) {
    int m = tid / 3, k = tid % 3;
    float s1 = 0.f, s2 = 0.f;
    #pragma unroll
    for (int c = 0; c < 6; c++) {
      float g = gis[c * 3 + k];
      s1 = fmaf(Wa [m * 6 + c], g, s1);
      s2 = fmaf(Wav[m * 6 + c], g, s2);
    }
    kis[m * 3 + k] = s1; vis[k * 3 + m] = s2;
  }

  float km0 = 0.f, km1 = 0.f, km2 = 0.f;
  #pragma unroll
  for (int s = 0; s < 4; s++) {
    const float* pk = ws + PBKM_OFF + (b * 4 + s) * 3;
    km0 = fmaxf(km0, pk[0]); km1 = fmaxf(km1, pk[1]); km2 = fmaxf(km2, pk[2]);
  }

  const float KS = 1.4426950408889634f * 0.57735026918962576f;  // log2e/sqrt(3)
  const float* xb = x + (size_t)b * 6 * N_PTS;

  union U2 { uint2 u; f16x4 h; };
  U2 qb[4];
  f32x4 cb[4];
  f32x4 acc0[4], acc1[4];
  #pragma unroll
  for (int rt = 0; rt < 4; rt++) {
    const int n = nb + rt * 16 + col;
    float q0 = 0, q1 = 0, q2 = 0;
    #pragma unroll
    for (int c = 0; c < 6; c++) {
      float xv = xb[c * N_PTS + n];
      q0 = fmaf(xv, Wc[c], q0); q1 = fmaf(xv, Wc[6 + c], q1); q2 = fmaf(xv, Wc[12 + c], q2);
    }
    q0 *= KS; q1 *= KS; q2 *= KS;
    float Mp = fabsf(q0) * km0 + fabsf(q1) * km1 + fabsf(q2) * km2;
    qb[rt].u.x = qb[rt].u.y = 0;
    if (hi4 == 0) {
      qb[rt].u.x = h2_bits(__builtin_amdgcn_cvt_pkrtz(q0, q1));
      qb[rt].u.y = h2_bits(__builtin_amdgcn_cvt_pkrtz(q2, 0.f));
    }
    cb[rt] = (f32x4){ -Mp, -Mp, -Mp, -Mp };
    acc0[rt] = (f32x4){0,0,0,0};
    acc1[rt] = (f32x4){0,0,0,0};
  }

  unsigned ki_ = (hi4 == 0) ? (unsigned)(kq * 1024 + col * 2) : 4096u;
  const unsigned kd = (hi4 == 0) ? 32u : 0u;
  unsigned vi_ = (col < 4) ? (unsigned)(col * 1028 + kq * 256 + 2 * hi4) : 4112u;
  const unsigned vd = (col < 4) ? 8u : 0u;

  U2 Kc, Vc;
  Kc.u = *(const uint2*)&kt[ki_];
  Vc.u = *(const uint2*)&vt[vi_];

  #pragma unroll 2
  for (int i = 0; i < 32; i++) {
    ki_ += kd; vi_ += vd;
    U2 Kn, Vn;                     // prefetch (last-iter read lands in pad, unused)
    Kn.u = *(const uint2*)&kt[ki_];
    Vn.u = *(const uint2*)&vt[vi_];

    f32x4 s[4];
    __builtin_amdgcn_s_setprio(1);
    #pragma unroll
    for (int rt = 0; rt < 4; rt++)
      s[rt] = __builtin_amdgcn_mfma_f32_16x16x16f16(Kc.h, qb[rt].h, cb[rt], 0, 0, 0);
    __builtin_amdgcn_s_setprio(0);

    U2 P[4];
    #pragma unroll
    for (int rt = 0; rt < 4; rt++) {
      float e0 = __builtin_amdgcn_exp2f(s[rt][0]);
      float e1 = __builtin_amdgcn_exp2f(s[rt][1]);
      float e2 = __builtin_amdgcn_exp2f(s[rt][2]);
      float e3 = __builtin_amdgcn_exp2f(s[rt][3]);
      P[rt].u.x = h2_bits(__builtin_amdgcn_cvt_pkrtz(e0, e1));
      P[rt].u.y = h2_bits(__builtin_amdgcn_cvt_pkrtz(e2, e3));
    }

    __builtin_amdgcn_s_setprio(1);
    if (i & 1) {
      #pragma unroll
      for (int rt = 0; rt < 4; rt++)
        acc1[rt] = __builtin_amdgcn_mfma_f32_16x16x16f16(Vc.h, P[rt].h, acc1[rt], 0, 0, 0);
    } else {
      #pragma unroll
      for (int rt = 0; rt < 4; rt++)
        acc0[rt] = __builtin_amdgcn_mfma_f32_16x16x16f16(Vc.h, P[rt].h, acc0[rt], 0, 0, 0);
    }
    __builtin_amdgcn_s_setprio(0);
    Kc = Kn; Vc = Vn;
  }

  if (hi4 == 0) {
    #pragma unroll
    for (int rt = 0; rt < 4; rt++)
      cross[kq][rt * 16 + col] = make_float4(
        acc0[rt][0] + acc1[rt][0], acc0[rt][1] + acc1[rt][1],
        acc0[rt][2] + acc1[rt][2], acc0[rt][3] + acc1[rt][3]);
  }
  __syncthreads();

  if (tid < 64) {
    const int ri = tid, n = nb + ri;
    float4 c0 = cross[0][ri], c1 = cross[1][ri], c2 = cross[2][ri], c3 = cross[3][ri];
    float w0 = c0.x + c1.x + c2.x + c3.x;
    float w1 = c0.y + c1.y + c2.y + c3.y;
    float w2 = c0.z + c1.z + c2.z + c3.z;
    float dd = c0.w + c1.w + c2.w + c3.w;

    float a0 = 0, a1 = 0, a2 = 0;
    #pragma unroll
    for (int c = 0; c < 6; c++) {
      float xv = xb[c * N_PTS + n];
      a0 = fmaf(xv, Wc[c], a0); a1 = fmaf(xv, Wc[6 + c], a1); a2 = fmaf(xv, Wc[12 + c], a2);
    }
    a0 *= KS; a1 *= KS; a2 *= KS;

    float sk0 = a0 * kis[0] + a1 * kis[3] + a2 * kis[6];
    float sk1 = a0 * kis[1] + a1 * kis[4] + a2 * kis[7];
    float sk2 = a0 * kis[2] + a1 * kis[5] + a2 * kis[8];
    float mm  = fmaxf(fmaxf(sk0, sk1), sk2);
    float e0 = __builtin_amdgcn_exp2f(sk0 - mm);
    float e1 = __builtin_amdgcn_exp2f(sk1 - mm);
    float e2 = __builtin_amdgcn_exp2f(sk2 - mm);
    float rs = 1.f / (e0 + e1 + e2);
    float fi0 = (e0 * vis[0] + e1 * vis[3] + e2 * vis[6]) * rs;
    float fi1 = (e0 * vis[1] + e1 * vis[4] + e2 * vis[7]) * rs;
    float fi2 = (e0 * vis[2] + e1 * vis[5] + e2 * vis[8]) * rs;
    float rinv = 1.f / dd;
    float cf[6] = { fi0, fi1, fi2, w0 * rinv, w1 * rinv, w2 * rinv };

    float mu = (cf[0] + cf[1] + cf[2] + cf[3] + cf[4] + cf[5]) * (1.f / 6.f);
    float var = 0.f;
    #pragma unroll
    for (int i = 0; i < 6; i++) { float t = cf[i] - mu; var += t * t; }
    var *= (1.f / 6.f);
    float rn = rsqrtf(var + 1e-5f);
    float cfn[6];
    #pragma unroll
    for (int i = 0; i < 6; i++) cfn[i] = (cf[i] - mu) * rn * lng[i] + lnb[i];

    float v12[12];
    #pragma unroll
    for (int o = 0; o < 6; o++) {
      float s = 0.f;
      #pragma unroll
      for (int c = 0; c < 6; c++) s += Wd[o * 6 + c] * cfn[c];
      yout[(size_t)b * (6 * N_PTS) + o * N_PTS + n] = s;
      v12[o] = s; v12[6 + o] = s * s;
    }
    #pragma unroll
    for (int j = 0; j < 12; j++) v12[j] = wave_reduce_sum(v12[j]);
    if (tid == 0) {
      float* part = ws + PART_OFF + blk * 12;
      for (int j = 0; j < 12; j++) part[j] = v12[j];
    }
  }
}

// ------------------------------------------------------------- bn stats ---
__global__ __launch_bounds__(256)
void bnstats_kernel(const float* __restrict__ bng, const float* __restrict__ bnbt,
                    float* __restrict__ ws)
{
  __shared__ float cp[48];
  const int tid = threadIdx.x;
  const float* part = ws + PART_OFF;
  float v[12];
  #pragma unroll
  for (int j = 0; j < 12; j++)
    v[j] = part[tid * 12 + j] + part[(tid + 256) * 12 + j]
         + part[(tid + 512) * 12 + j] + part[(tid + 768) * 12 + j];
  #pragma unroll
  for (int j = 0; j < 12; j++) v[j] = wave_reduce_sum(v[j]);
  const int lane = tid & 63, wid = tid >> 6;
  if (lane == 0) { for (int j = 0; j < 12; j++) cp[wid * 12 + j] = v[j]; }
  __syncthreads();
  if (tid == 0) {
    const float inv = 1.f / 65536.f;   // B * N
    for (int o = 0; o < 6; o++) {
      float s1 = cp[o] + cp[12 + o] + cp[24 + o] + cp[36 + o];
      float s2 = cp[6 + o] + cp[18 + o] + cp[30 + o] + cp[42 + o];
      float mean = s1 * inv;
      float varr = s2 * inv - mean * mean;
      float sc = bng[o] * rsqrtf(varr + 1e-5f);
      ws[BNS_OFF + o] = sc;
      ws[BNB_OFF + o] = bnbt[o] - mean * sc;
    }
  }
}

// ------------------------------------------------------------- finalize ---
__global__ __launch_bounds__(256)
void final_kernel(const float* __restrict__ x, const float* __restrict__ ws,
                  float* __restrict__ out)
{
  const int i = blockIdx.x * 256 + threadIdx.x;   // 393216 total
  const int ch = (i >> 15) % 6;
  float v = out[i] * ws[BNS_OFF + ch] + ws[BNB_OFF + ch] + x[i];
  out[i] = v >= 0.f ? v : 0.2f * v;
}

// ---------------------------------------------------------------- launch --
extern "C" void kernel_launch(void* const* d_in, const int* in_sizes, int n_in,
                              void* d_out, int out_size, void* d_ws, size_t ws_size,
                              hipStream_t stream)
{
  const float* x      = (const float*)d_in[0];
  const float* curves = (const float*)d_in[1];
  const float* Wa     = (const float*)d_in[2];
  const float* Wav    = (const float*)d_in[3];
  const float* Wb     = (const float*)d_in[4];
  const float* Wbv    = (const float*)d_in[5];
  const float* Wc     = (const float*)d_in[6];
  const float* Wd     = (const float*)d_in[7];
  const float* bng    = (const float*)d_in[8];
  const float* bnbt   = (const float*)d_in[9];
  const float* Watt   = (const float*)d_in[10];
  const float* lng    = (const float*)d_in[11];
  const float* lnbt   = (const float*)d_in[12];
  const float* Wpl    = (const float*)d_in[13];
  const float* bpl    = (const float*)d_in[14];
  const float* Wpn    = (const float*)d_in[15];
  const float* bpn    = (const float*)d_in[16];
  float* out = (float*)d_out;
  float* ws  = (float*)d_ws;

  prep_kernel<<<14, 256, 0, stream>>>(curves, Watt, Wb, Wbv, Wpn, bpn, ws);
  attn_kernel<<<1024, 256, 0, stream>>>(x, Wc, Wd, lng, lnbt,
                                        Wa, Wav, Wpl, bpl, ws, out);
  bnstats_kernel<<<1, 256, 0, stream>>>(bng, bnbt, ws);
  final_kernel<<<1536, 256, 0, stream>>>(x, ws, out);
}

// Round 10
// 34.380 us; speedup vs baseline: 1.0573x; 1.0573x over previous
//
#include <hip/hip_runtime.h>
#include <math.h>

#define N_PTS 32768
#define LL    2048

// d_ws dword/float offsets
#define KT_U      0          // uint: [2][2048][2] K frag table {k0k1, k2_0}
#define VT_U      8192       // uint: [2][4][1024] V planes (v0,v1,v2,ones) f16-pairs
#define PART_OFF  16384      // float [1024][12] BN partials
#define MS_OFF    28672      // [6][2]  {m, expsum}
#define W_OFF     28684      // [6][6]  exp-weighted sums
#define CS_OFF    28720      // [3][6]  colsum batch0
#define PBKM_OFF  28738      // [8][3]  per-kvblock |k| max
#define BNS_OFF   28762      // [6]
#define BNB_OFF   28768      // [6]

typedef __fp16 h2    __attribute__((ext_vector_type(2)));
typedef __fp16 f16x4 __attribute__((ext_vector_type(4)));
typedef float  f32x4 __attribute__((ext_vector_type(4)));

__device__ __forceinline__ unsigned h2_bits(h2 h){
  union { h2 h; unsigned u; } x; x.h = h; return x.u;
}
__device__ __forceinline__ float wave_reduce_sum(float v){
  #pragma unroll
  for (int off = 32; off; off >>= 1) v += __shfl_xor(v, off, 64);
  return v;
}
__device__ __forceinline__ float wave_reduce_max(float v){
  #pragma unroll
  for (int off = 32; off; off >>= 1) v = fmaxf(v, __shfl_xor(v, off, 64));
  return v;
}

// ---------------------------------------------------------------- prep ----
// 14 blocks x 256. Blocks 0-5: per-(b,nc) global stats (max, expsum, W, CS).
// Blocks 6-13: kv table build; per-block |k| max into PBKM slots.
__global__ __launch_bounds__(256)
void prep_kernel(const float* __restrict__ curves, const float* __restrict__ Watt,
                 const float* __restrict__ Wb,  const float* __restrict__ Wbv,
                 const float* __restrict__ Wpn, const float* __restrict__ bpn,
                 float* __restrict__ ws)
{
  const int blk = blockIdx.x, tid = threadIdx.x;
  const int lane = tid & 63, wid = tid >> 6;
  __shared__ float sred[4 * 13];
  __shared__ float msh;

  float watt[6];
  #pragma unroll
  for (int c = 0; c < 6; c++) watt[c] = Watt[c];

  if (blk < 6) {
    const int b = blk / 3, nc = blk % 3;
    const float* cb = curves + b * 18 * LL;
    float av[8], pm = -1e30f;
    #pragma unroll
    for (int k = 0; k < 8; k++) {
      const int l = tid + k * 256;
      float s = 0.f;
      #pragma unroll
      for (int c = 0; c < 6; c++) s = fmaf(cb[(c * 3 + nc) * LL + l], watt[c], s);
      av[k] = s; pm = fmaxf(pm, s);
    }
    pm = wave_reduce_max(pm);
    if (lane == 0) sred[wid] = pm;
    __syncthreads();
    if (tid == 0) msh = fmaxf(fmaxf(sred[0], sred[1]), fmaxf(sred[2], sred[3]));
    __syncthreads();
    const float m = msh;

    float vals[13];
    #pragma unroll
    for (int j = 0; j < 13; j++) vals[j] = 0.f;
    #pragma unroll
    for (int k = 0; k < 8; k++) {
      const int l = tid + k * 256;
      float e = __expf(av[k] - m);
      vals[0] += e;
      #pragma unroll
      for (int c = 0; c < 6; c++) {
        float v = cb[(c * 3 + nc) * LL + l];
        vals[1 + c] = fmaf(v, e, vals[1 + c]);
        if (b == 0) vals[7 + c] += v;
      }
    }
    __syncthreads();
    #pragma unroll
    for (int j = 0; j < 13; j++) vals[j] = wave_reduce_sum(vals[j]);
    if (lane == 0) { for (int j = 0; j < 13; j++) sred[wid * 13 + j] = vals[j]; }
    __syncthreads();
    if (tid == 0) {
      ws[MS_OFF + blk * 2] = m;
      for (int j = 0; j < 13; j++) {
        float s = sred[j] + sred[13 + j] + sred[26 + j] + sred[39 + j];
        if (j == 0) ws[MS_OFF + blk * 2 + 1] = s;
        else if (j < 7) ws[W_OFF + blk * 6 + (j - 1)] = s;
        else if (b == 0) ws[CS_OFF + nc * 6 + (j - 7)] = s;
      }
    }
  } else {
    const int idx = (blk - 6) * 256 + tid;   // 0..2047
    const int b = idx >> 10, pp = idx & 1023, l = pp * 2;
    const float* cb = curves + b * 18 * LL;

    float2 cv[6][3], pv[6][3];
    #pragma unroll
    for (int c = 0; c < 6; c++)
      #pragma unroll
      for (int nc = 0; nc < 3; nc++) {
        cv[c][nc] = *(const float2*)&cb[(c * 3 + nc) * LL + l];
        pv[c][nc] = *(const float2*)&curves[(c * 3 + nc) * LL + l];  // batch 0
      }
    float a[3][2];
    #pragma unroll
    for (int nc = 0; nc < 3; nc++) {
      float sx = 0.f, sy = 0.f;
      #pragma unroll
      for (int c = 0; c < 6; c++) {
        sx = fmaf(cv[c][nc].x, watt[c], sx);
        sy = fmaf(cv[c][nc].y, watt[c], sy);
      }
      a[nc][0] = sx; a[nc][1] = sy;
    }

    float wb_r[18], wbv_r[18];
    #pragma unroll
    for (int i = 0; i < 18; i++) { wb_r[i] = Wb[i]; wbv_r[i] = Wbv[i]; }
    const float wn0 = (Wpn[0] + Wpn[3] + Wpn[6]) * (1.f / 3.f);
    const float wn1 = (Wpn[1] + Wpn[4] + Wpn[7]) * (1.f / 3.f);
    const float wn2 = (Wpn[2] + Wpn[5] + Wpn[8]) * (1.f / 3.f);
    const float bnb = (bpn[0] + bpn[1] + bpn[2]) * (1.f / 3.f);

    float kk[2][3], vv[2][3], km[3] = {0.f, 0.f, 0.f};
    #pragma unroll
    for (int e = 0; e < 2; e++) {
      float a0 = a[0][e], a1 = a[1][e], a2 = a[2][e];
      float mm = fmaxf(fmaxf(a0, a1), a2);
      float e0 = __expf(a0 - mm), e1 = __expf(a1 - mm), e2 = __expf(a2 - mm);
      float r = 1.f / (e0 + e1 + e2);
      float ga[6];
      #pragma unroll
      for (int c = 0; c < 6; c++) {
        float c0 = e ? cv[c][0].y : cv[c][0].x;
        float c1 = e ? cv[c][1].y : cv[c][1].x;
        float c2 = e ? cv[c][2].y : cv[c][2].x;
        float p0 = e ? pv[c][0].y : pv[c][0].x;
        float p1 = e ? pv[c][1].y : pv[c][1].x;
        float p2 = e ? pv[c][2].y : pv[c][2].x;
        float intra = (c0 * e0 + c1 * e1 + c2 * e2) * r;
        float pn = p0 * wn0 + p1 * wn1 + p2 * wn2 + bnb;
        ga[c] = intra + pn;
      }
      float k0 = 0, k1 = 0, k2 = 0, v0 = 0, v1 = 0, v2 = 0;
      #pragma unroll
      for (int c = 0; c < 6; c++) {
        k0 += wb_r[c] * ga[c];  k1 += wb_r[6 + c] * ga[c];  k2 += wb_r[12 + c] * ga[c];
        v0 += wbv_r[c] * ga[c]; v1 += wbv_r[6 + c] * ga[c]; v2 += wbv_r[12 + c] * ga[c];
      }
      kk[e][0] = k0; kk[e][1] = k1; kk[e][2] = k2;
      vv[e][0] = v0; vv[e][1] = v1; vv[e][2] = v2;
      km[0] = fmaxf(km[0], fabsf(k0));
      km[1] = fmaxf(km[1], fabsf(k1));
      km[2] = fmaxf(km[2], fabsf(k2));
    }
    unsigned* ktg = (unsigned*)ws + KT_U + b * 4096;
    ktg[4 * pp + 0] = h2_bits(__builtin_amdgcn_cvt_pkrtz(kk[0][0], kk[0][1]));
    ktg[4 * pp + 1] = h2_bits(__builtin_amdgcn_cvt_pkrtz(kk[0][2], 0.f));
    ktg[4 * pp + 2] = h2_bits(__builtin_amdgcn_cvt_pkrtz(kk[1][0], kk[1][1]));
    ktg[4 * pp + 3] = h2_bits(__builtin_amdgcn_cvt_pkrtz(kk[1][2], 0.f));
    unsigned* vtg = (unsigned*)ws + VT_U + b * 4096;
    vtg[0 * 1024 + pp] = h2_bits(__builtin_amdgcn_cvt_pkrtz(vv[0][0], vv[1][0]));
    vtg[1 * 1024 + pp] = h2_bits(__builtin_amdgcn_cvt_pkrtz(vv[0][1], vv[1][1]));
    vtg[2 * 1024 + pp] = h2_bits(__builtin_amdgcn_cvt_pkrtz(vv[0][2], vv[1][2]));
    vtg[3 * 1024 + pp] = h2_bits(__builtin_amdgcn_cvt_pkrtz(1.f, 1.f));

    #pragma unroll
    for (int j = 0; j < 3; j++) km[j] = wave_reduce_max(km[j]);
    if (lane == 0) { for (int j = 0; j < 3; j++) sred[wid * 3 + j] = km[j]; }
    __syncthreads();
    if (tid == 0) {
      for (int j = 0; j < 3; j++)
        ws[PBKM_OFF + (blk - 6) * 3 + j] =
          fmaxf(fmaxf(sred[j], sred[3 + j]), fmaxf(sred[6 + j], sred[9 + j]));
    }
  }
}

// ---------------------------------------------------------------- main ----
// 1024 blocks x 256 thr (4 waves). Block = 64 rows. Wave w: rp=w>>1 (2 row-
// tiles of 16), key-half kh=w&1 (64 chunks of 16 keys). Explicit 2-stage
// software pipeline: scores for chunk i+1 computed at top of iteration i
// (from K resident since iter i-1), exp consumes the PREVIOUS iteration's
// scores -> score-MFMA latency hidden by a full iteration. Reads run 2
// chunks ahead; dual PV accumulators.
__global__ __launch_bounds__(256, 4)
void attn_kernel(const float* __restrict__ x,  const float* __restrict__ Wc,
                 const float* __restrict__ Wd, const float* __restrict__ lng,
                 const float* __restrict__ lnb,
                 const float* __restrict__ Wa, const float* __restrict__ Wav,
                 const float* __restrict__ Wpl, const float* __restrict__ bpl,
                 float* __restrict__ ws, float* __restrict__ yout)
{
  __shared__ __align__(16) unsigned kt[4224];  // 2048 keys x 2 dw; zeros @4096-97
  __shared__ __align__(16) unsigned vt[4224];  // 4 planes x 1028; zeros @4112-13
  __shared__ float4 cross[2][64];
  __shared__ float gis[18], kis[9], vis[9];
  const int tid  = threadIdx.x, blk = blockIdx.x;
  const int lane = tid & 63, w = tid >> 6;
  const int col  = lane & 15, hi4 = lane >> 4;
  const int rp   = w >> 1, kh = w & 1;
  const int rbase = blk * 64;
  const int b    = rbase >> 15;
  const int nb   = rbase & (N_PTS - 1);

  // ---- stage K/V tables ----
  {
    const uint4* ktg = (const uint4*)((const unsigned*)ws + KT_U + b * 4096);
    uint4* kt4 = (uint4*)kt;
    for (int i = tid; i < 1024; i += 256) kt4[i] = ktg[i];
    const uint2* vtg2 = (const uint2*)((const unsigned*)ws + VT_U + b * 4096);
    for (int i = tid; i < 2048; i += 256) {
      int pl = i >> 9, off = (i & 511) << 1;
      *(uint2*)&vt[pl * 1028 + off] = vtg2[i];
    }
    if (tid < 2) { kt[4096 + tid] = 0; vt[4112 + tid] = 0; }
  }
  // gis by lanes 0-17 (overlaps staging)
  if (tid < 18) {
    int c = tid / 3, m = tid % 3;
    float pl_ = bpl[m];
    #pragma unroll
    for (int k = 0; k < 3; k++)
      pl_ = fmaf(Wpl[m * 3 + k], ws[CS_OFF + k * 6 + c] * (1.f / LL), pl_);
    gis[c * 3 + m] = ws[W_OFF + (b * 3 + m) * 6 + c] / ws[MS_OFF + (b * 3 + m) * 2 + 1] + pl_;
  }
  __syncthreads();
  if (tid < 9) {
    int m = tid / 3, k = tid % 3;
    float s1 = 0.f, s2 = 0.f;
    #pragma unroll
    for (int c = 0; c < 6; c++) {
      float g = gis[c * 3 + k];
      s1 = fmaf(Wa [m * 6 + c], g, s1);
      s2 = fmaf(Wav[m * 6 + c], g, s2);
    }
    kis[m * 3 + k] = s1; vis[k * 3 + m] = s2;
  }

  float km0 = 0.f, km1 = 0.f, km2 = 0.f;
  #pragma unroll
  for (int s = 0; s < 4; s++) {
    const float* pk = ws + PBKM_OFF + (b * 4 + s) * 3;
    km0 = fmaxf(km0, pk[0]); km1 = fmaxf(km1, pk[1]); km2 = fmaxf(km2, pk[2]);
  }

  // q for both row-tiles
  const int nA = nb + rp * 32 + col, nBr = nA + 16;
  const float* xb = x + (size_t)b * 6 * N_PTS;
  float q0A = 0, q1A = 0, q2A = 0, q0B = 0, q1B = 0, q2B = 0;
  #pragma unroll
  for (int c = 0; c < 6; c++) {
    float xvA = xb[c * N_PTS + nA], xvB = xb[c * N_PTS + nBr];
    q0A = fmaf(xvA, Wc[c], q0A); q1A = fmaf(xvA, Wc[6 + c], q1A); q2A = fmaf(xvA, Wc[12 + c], q2A);
    q0B = fmaf(xvB, Wc[c], q0B); q1B = fmaf(xvB, Wc[6 + c], q1B); q2B = fmaf(xvB, Wc[12 + c], q2B);
  }
  const float KS = 1.4426950408889634f * 0.57735026918962576f;  // log2e/sqrt(3)
  q0A *= KS; q1A *= KS; q2A *= KS; q0B *= KS; q1B *= KS; q2B *= KS;
  const float MpA = fabsf(q0A) * km0 + fabsf(q1A) * km1 + fabsf(q2A) * km2;
  const float MpB = fabsf(q0B) * km0 + fabsf(q1B) * km1 + fabsf(q2B) * km2;

  union U2 { uint2 u; f16x4 h; };
  U2 qbA, qbB;
  qbA.u.x = qbA.u.y = qbB.u.x = qbB.u.y = 0;
  if (hi4 == 0) {
    qbA.u.x = h2_bits(__builtin_amdgcn_cvt_pkrtz(q0A, q1A));
    qbA.u.y = h2_bits(__builtin_amdgcn_cvt_pkrtz(q2A, 0.f));
    qbB.u.x = h2_bits(__builtin_amdgcn_cvt_pkrtz(q0B, q1B));
    qbB.u.y = h2_bits(__builtin_amdgcn_cvt_pkrtz(q2B, 0.f));
  }
  f32x4 cbA = { -MpA, -MpA, -MpA, -MpA };
  f32x4 cbB = { -MpB, -MpB, -MpB, -MpB };
  f32x4 aA0 = {0,0,0,0}, aA1 = {0,0,0,0}, aB0 = {0,0,0,0}, aB1 = {0,0,0,0};

  unsigned ki_ = (hi4 == 0) ? (unsigned)(kh * 2048 + col * 2) : 4096u;
  const unsigned kd = (hi4 == 0) ? 32u : 0u;
  unsigned vi_ = (col < 4) ? (unsigned)(col * 1028 + kh * 512 + 2 * hi4) : 4112u;
  const unsigned vd = (col < 4) ? 8u : 0u;

  // ---- pipeline prologue: chunk0 scores, chunk0/1 frags resident ----
  U2 Kc, Vc, Kn, Vn;
  Kc.u = *(const uint2*)&kt[ki_];          // chunk 0
  Vc.u = *(const uint2*)&vt[vi_];
  ki_ += kd; vi_ += vd;
  Kn.u = *(const uint2*)&kt[ki_];          // chunk 1
  Vn.u = *(const uint2*)&vt[vi_];
  f32x4 sAc = __builtin_amdgcn_mfma_f32_16x16x16f16(Kc.h, qbA.h, cbA, 0, 0, 0);
  f32x4 sBc = __builtin_amdgcn_mfma_f32_16x16x16f16(Kc.h, qbB.h, cbB, 0, 0, 0);

  #pragma unroll 2
  for (int i = 0; i < 62; i++) {
    // scores for chunk i+1 (K resident since last iteration)
    f32x4 sAn = __builtin_amdgcn_mfma_f32_16x16x16f16(Kn.h, qbA.h, cbA, 0, 0, 0);
    f32x4 sBn = __builtin_amdgcn_mfma_f32_16x16x16f16(Kn.h, qbB.h, cbB, 0, 0, 0);
    // issue K read for chunk i+2
    ki_ += kd;
    Kn.u = *(const uint2*)&kt[ki_];
    // exp/cvt on chunk i scores (computed a full iteration ago)
    float eA0 = __builtin_amdgcn_exp2f(sAc[0]);
    float eA1 = __builtin_amdgcn_exp2f(sAc[1]);
    float eA2 = __builtin_amdgcn_exp2f(sAc[2]);
    float eA3 = __builtin_amdgcn_exp2f(sAc[3]);
    float eB0 = __builtin_amdgcn_exp2f(sBc[0]);
    float eB1 = __builtin_amdgcn_exp2f(sBc[1]);
    float eB2 = __builtin_amdgcn_exp2f(sBc[2]);
    float eB3 = __builtin_amdgcn_exp2f(sBc[3]);
    U2 PA, PB;
    PA.u.x = h2_bits(__builtin_amdgcn_cvt_pkrtz(eA0, eA1));
    PA.u.y = h2_bits(__builtin_amdgcn_cvt_pkrtz(eA2, eA3));
    PB.u.x = h2_bits(__builtin_amdgcn_cvt_pkrtz(eB0, eB1));
    PB.u.y = h2_bits(__builtin_amdgcn_cvt_pkrtz(eB2, eB3));
    if (i & 1) {
      aA1 = __builtin_amdgcn_mfma_f32_16x16x16f16(Vc.h, PA.h, aA1, 0, 0, 0);
      aB1 = __builtin_amdgcn_mfma_f32_16x16x16f16(Vc.h, PB.h, aB1, 0, 0, 0);
    } else {
      aA0 = __builtin_amdgcn_mfma_f32_16x16x16f16(Vc.h, PA.h, aA0, 0, 0, 0);
      aB0 = __builtin_amdgcn_mfma_f32_16x16x16f16(Vc.h, PB.h, aB0, 0, 0, 0);
    }
    // rotate V and issue V read for chunk i+2
    Vc = Vn;
    vi_ += vd;
    Vn.u = *(const uint2*)&vt[vi_];
    sAc = sAn; sBc = sBn;
  }
  // ---- epilogue: chunks 62, 63 ----
  {
    f32x4 sAn = __builtin_amdgcn_mfma_f32_16x16x16f16(Kn.h, qbA.h, cbA, 0, 0, 0);
    f32x4 sBn = __builtin_amdgcn_mfma_f32_16x16x16f16(Kn.h, qbB.h, cbB, 0, 0, 0);
    #pragma unroll
    for (int e = 0; e < 2; e++) {
      float e0 = __builtin_amdgcn_exp2f(sAc[0]);
      float e1 = __builtin_amdgcn_exp2f(sAc[1]);
      float e2 = __builtin_amdgcn_exp2f(sAc[2]);
      float e3 = __builtin_amdgcn_exp2f(sAc[3]);
      float f0 = __builtin_amdgcn_exp2f(sBc[0]);
      float f1 = __builtin_amdgcn_exp2f(sBc[1]);
      float f2 = __builtin_amdgcn_exp2f(sBc[2]);
      float f3 = __builtin_amdgcn_exp2f(sBc[3]);
      U2 PA, PB;
      PA.u.x = h2_bits(__builtin_amdgcn_cvt_pkrtz(e0, e1));
      PA.u.y = h2_bits(__builtin_amdgcn_cvt_pkrtz(e2, e3));
      PB.u.x = h2_bits(__builtin_amdgcn_cvt_pkrtz(f0, f1));
      PB.u.y = h2_bits(__builtin_amdgcn_cvt_pkrtz(f2, f3));
      if (e == 0) {
        aA0 = __builtin_amdgcn_mfma_f32_16x16x16f16(Vc.h, PA.h, aA0, 0, 0, 0);
        aB0 = __builtin_amdgcn_mfma_f32_16x16x16f16(Vc.h, PB.h, aB0, 0, 0, 0);
        Vc = Vn; sAc = sAn; sBc = sBn;
      } else {
        aA1 = __builtin_amdgcn_mfma_f32_16x16x16f16(Vc.h, PA.h, aA1, 0, 0, 0);
        aB1 = __builtin_amdgcn_mfma_f32_16x16x16f16(Vc.h, PB.h, aB1, 0, 0, 0);
      }
    }
  }

  if (hi4 == 0) {
    cross[kh][rp * 32 + col] =
      make_float4(aA0[0] + aA1[0], aA0[1] + aA1[1], aA0[2] + aA1[2], aA0[3] + aA1[3]);
    cross[kh][rp * 32 + 16 + col] =
      make_float4(aB0[0] + aB1[0], aB0[1] + aB1[1], aB0[2] + aB1[2], aB0[3] + aB1[3]);
  }
  __syncthreads();

  if (tid < 64) {
    const int ri = tid, n = nb + ri;
    float4 c0 = cross[0][ri], c1 = cross[1][ri];
    float w0 = c0.x + c1.x, w1 = c0.y + c1.y, w2 = c0.z + c1.z, dd = c0.w + c1.w;

    float a0 = 0, a1 = 0, a2 = 0;
    #pragma unroll
    for (int c = 0; c < 6; c++) {
      float xv = xb[c * N_PTS + n];
      a0 = fmaf(xv, Wc[c], a0); a1 = fmaf(xv, Wc[6 + c], a1); a2 = fmaf(xv, Wc[12 + c], a2);
    }
    a0 *= KS; a1 *= KS; a2 *= KS;

    float sk0 = a0 * kis[0] + a1 * kis[3] + a2 * kis[6];
    float sk1 = a0 * kis[1] + a1 * kis[4] + a2 * kis[7];
    float sk2 = a0 * kis[2] + a1 * kis[5] + a2 * kis[8];
    float mm  = fmaxf(fmaxf(sk0, sk1), sk2);
    float e0 = __builtin_amdgcn_exp2f(sk0 - mm);
    float e1 = __builtin_amdgcn_exp2f(sk1 - mm);
    float e2 = __builtin_amdgcn_exp2f(sk2 - mm);
    float rs = 1.f / (e0 + e1 + e2);
    float fi0 = (e0 * vis[0] + e1 * vis[3] + e2 * vis[6]) * rs;
    float fi1 = (e0 * vis[1] + e1 * vis[4] + e2 * vis[7]) * rs;
    float fi2 = (e0 * vis[2] + e1 * vis[5] + e2 * vis[8]) * rs;
    float rinv = 1.f / dd;
    float cf[6] = { fi0, fi1, fi2, w0 * rinv, w1 * rinv, w2 * rinv };

    float mu = (cf[0] + cf[1] + cf[2] + cf[3] + cf[4] + cf[5]) * (1.f / 6.f);
    float var = 0.f;
    #pragma unroll
    for (int i = 0; i < 6; i++) { float t = cf[i] - mu; var += t * t; }
    var *= (1.f / 6.f);
    float rn = rsqrtf(var + 1e-5f);
    float cfn[6];
    #pragma unroll
    for (int i = 0; i < 6; i++) cfn[i] = (cf[i] - mu) * rn * lng[i] + lnb[i];

    float v12[12];
    #pragma unroll
    for (int o = 0; o < 6; o++) {
      float s = 0.f;
      #pragma unroll
      for (int c = 0; c < 6; c++) s += Wd[o * 6 + c] * cfn[c];
      yout[(size_t)b * (6 * N_PTS) + o * N_PTS + n] = s;
      v12[o] = s; v12[6 + o] = s * s;
    }
    #pragma unroll
    for (int j = 0; j < 12; j++) v12[j] = wave_reduce_sum(v12[j]);
    if (tid == 0) {
      float* part = ws + PART_OFF + blk * 12;
      for (int j = 0; j < 12; j++) part[j] = v12[j];
    }
  }
}

// ------------------------------------------------- fused bnstats+final ----
// 384 blocks x 256 thr; each block redundantly reduces the 1024x12 partials
// (identical deterministic result per block), then applies BN + residual +
// LeakyReLU to its 1024-element slice (one float4 per thread).
__global__ __launch_bounds__(256)
void final_kernel(const float* __restrict__ x,
                  const float* __restrict__ bng, const float* __restrict__ bnbt,
                  const float* __restrict__ ws, float* __restrict__ out)
{
  __shared__ float cp[48];
  __shared__ float sc_s[6], sh_s[6];
  const int tid = threadIdx.x, blk = blockIdx.x;
  const int lane = tid & 63, wid = tid >> 6;
  const float* part = ws + PART_OFF;

  float v[12];
  #pragma unroll
  for (int j = 0; j < 12; j++) v[j] = 0.f;
  #pragma unroll
  for (int k = 0; k < 4; k++) {
    const float* p = part + (tid * 4 + k) * 12;
    #pragma unroll
    for (int j = 0; j < 12; j++) v[j] += p[j];
  }
  #pragma unroll
  for (int j = 0; j < 12; j++) v[j] = wave_reduce_sum(v[j]);
  if (lane == 0) { for (int j = 0; j < 12; j++) cp[wid * 12 + j] = v[j]; }
  __syncthreads();
  if (tid < 6) {
    const float inv = 1.f / 65536.f;   // B * N
    float s1 = cp[tid] + cp[12 + tid] + cp[24 + tid] + cp[36 + tid];
    float s2 = cp[6 + tid] + cp[18 + tid] + cp[30 + tid] + cp[42 + tid];
    float mean = s1 * inv;
    float varr = s2 * inv - mean * mean;
    float sc = bng[tid] * rsqrtf(varr + 1e-5f);
    sc_s[tid] = sc;
    sh_s[tid] = bnbt[tid] - mean * sc;
  }
  __syncthreads();

  const int base = blk * 1024 + tid * 4;      // 393216 total
  const int ch = (base >> 15) % 6;
  const float sc = sc_s[ch], sh = sh_s[ch];
  float4 o = *(float4*)&out[base];
  float4 xx = *(const float4*)&x[base];
  float r[4] = { o.x * sc + sh + xx.x, o.y * sc + sh + xx.y,
                 o.z * sc + sh + xx.z, o.w * sc + sh + xx.w };
  #pragma unroll
  for (int j = 0; j < 4; j++) r[j] = r[j] >= 0.f ? r[j] : 0.2f * r[j];
  *(float4*)&out[base] = make_float4(r[0], r[1], r[2], r[3]);
}

// ---------------------------------------------------------------- launch --
extern "C" void kernel_launch(void* const* d_in, const int* in_sizes, int n_in,
                              void* d_out, int out_size, void* d_ws, size_t ws_size,
                              hipStream_t stream)
{
  const float* x      = (const float*)d_in[0];
  const float* curves = (const float*)d_in[1];
  const float* Wa     = (const float*)d_in[2];
  const float* Wav    = (const float*)d_in[3];
  const float* Wb     = (const float*)d_in[4];
  const float* Wbv    = (const float*)d_in[5];
  const float* Wc     = (const float*)d_in[6];
  const float* Wd     = (const float*)d_in[7];
  const float* bng    = (const float*)d_in[8];
  const float* bnbt   = (const float*)d_in[9];
  const float* Watt   = (const float*)d_in[10];
  const float* lng    = (const float*)d_in[11];
  const float* lnbt   = (const float*)d_in[12];
  const float* Wpl    = (const float*)d_in[13];
  const float* bpl    = (const float*)d_in[14];
  const float* Wpn    = (const float*)d_in[15];
  const float* bpn    = (const float*)d_in[16];
  float* out = (float*)d_out;
  float* ws  = (float*)d_ws;

  prep_kernel<<<14, 256, 0, stream>>>(curves, Watt, Wb, Wbv, Wpn, bpn, ws);
  attn_kernel<<<1024, 256, 0, stream>>>(x, Wc, Wd, lng, lnbt,
                                        Wa, Wav, Wpl, bpl, ws, out);
  final_kernel<<<384, 256, 0, stream>>>(x, bng, bnbt, ws, out);
}

// Round 12
// 33.632 us; speedup vs baseline: 1.0808x; 1.0222x over previous
//
#include <hip/hip_runtime.h>
#include <math.h>

#define N_PTS 32768
#define LL    2048

// d_ws dword/float offsets
#define KT_U      0          // uint: [2][4096] K pair-layout table
#define VT_U      8192       // uint: [2][4096] V pair-layout table
#define PART_OFF  16384      // float [256][12] BN partials
#define MS_OFF    28672      // [6][2]  {m, expsum}
#define W_OFF     28684      // [6][6]  exp-weighted sums
#define CS_OFF    28720      // [3][6]  colsum batch0
#define PBKM_OFF  28738      // [8][3]  per-kvblock |k| max
#define BNS_OFF   28762      // [6]
#define BNB_OFF   28768      // [6]

typedef __fp16 h2    __attribute__((ext_vector_type(2)));
typedef __fp16 f16x4 __attribute__((ext_vector_type(4)));
typedef float  f32x4 __attribute__((ext_vector_type(4)));

__device__ __forceinline__ unsigned h2_bits(h2 h){
  union { h2 h; unsigned u; } x; x.h = h; return x.u;
}
__device__ __forceinline__ float wave_reduce_sum(float v){
  #pragma unroll
  for (int off = 32; off; off >>= 1) v += __shfl_xor(v, off, 64);
  return v;
}
__device__ __forceinline__ float wave_reduce_max(float v){
  #pragma unroll
  for (int off = 32; off; off >>= 1) v = fmaxf(v, __shfl_xor(v, off, 64));
  return v;
}

// ---------------------------------------------------------------- prep ----
// 14 blocks x 256. Blocks 0-5: per-(b,nc) global stats (max, expsum, W, CS).
// Blocks 6-13: kv table build in chunk-PAIR layout; per-block |k| max.
__global__ __launch_bounds__(256)
void prep_kernel(const float* __restrict__ curves, const float* __restrict__ Watt,
                 const float* __restrict__ Wb,  const float* __restrict__ Wbv,
                 const float* __restrict__ Wpn, const float* __restrict__ bpn,
                 float* __restrict__ ws)
{
  const int blk = blockIdx.x, tid = threadIdx.x;
  const int lane = tid & 63, wid = tid >> 6;
  __shared__ float sred[4 * 13];
  __shared__ float msh;

  float watt[6];
  #pragma unroll
  for (int c = 0; c < 6; c++) watt[c] = Watt[c];

  if (blk < 6) {
    const int b = blk / 3, nc = blk % 3;
    const float* cb = curves + b * 18 * LL;
    float av[8], pm = -1e30f;
    #pragma unroll
    for (int k = 0; k < 8; k++) {
      const int l = tid + k * 256;
      float s = 0.f;
      #pragma unroll
      for (int c = 0; c < 6; c++) s = fmaf(cb[(c * 3 + nc) * LL + l], watt[c], s);
      av[k] = s; pm = fmaxf(pm, s);
    }
    pm = wave_reduce_max(pm);
    if (lane == 0) sred[wid] = pm;
    __syncthreads();
    if (tid == 0) msh = fmaxf(fmaxf(sred[0], sred[1]), fmaxf(sred[2], sred[3]));
    __syncthreads();
    const float m = msh;

    float vals[13];
    #pragma unroll
    for (int j = 0; j < 13; j++) vals[j] = 0.f;
    #pragma unroll
    for (int k = 0; k < 8; k++) {
      const int l = tid + k * 256;
      float e = __expf(av[k] - m);
      vals[0] += e;
      #pragma unroll
      for (int c = 0; c < 6; c++) {
        float v = cb[(c * 3 + nc) * LL + l];
        vals[1 + c] = fmaf(v, e, vals[1 + c]);
        if (b == 0) vals[7 + c] += v;
      }
    }
    __syncthreads();
    #pragma unroll
    for (int j = 0; j < 13; j++) vals[j] = wave_reduce_sum(vals[j]);
    if (lane == 0) { for (int j = 0; j < 13; j++) sred[wid * 13 + j] = vals[j]; }
    __syncthreads();
    if (tid == 0) {
      ws[MS_OFF + blk * 2] = m;
      for (int j = 0; j < 13; j++) {
        float s = sred[j] + sred[13 + j] + sred[26 + j] + sred[39 + j];
        if (j == 0) ws[MS_OFF + blk * 2 + 1] = s;
        else if (j < 7) ws[W_OFF + blk * 6 + (j - 1)] = s;
        else if (b == 0) ws[CS_OFF + nc * 6 + (j - 7)] = s;
      }
    }
  } else {
    const int idx = (blk - 6) * 256 + tid;   // 0..2047
    const int b = idx >> 10, pp = idx & 1023, l = pp * 2;
    const float* cb = curves + b * 18 * LL;

    float2 cv[6][3], pv[6][3];
    #pragma unroll
    for (int c = 0; c < 6; c++)
      #pragma unroll
      for (int nc = 0; nc < 3; nc++) {
        cv[c][nc] = *(const float2*)&cb[(c * 3 + nc) * LL + l];
        pv[c][nc] = *(const float2*)&curves[(c * 3 + nc) * LL + l];  // batch 0
      }
    float a[3][2];
    #pragma unroll
    for (int nc = 0; nc < 3; nc++) {
      float sx = 0.f, sy = 0.f;
      #pragma unroll
      for (int c = 0; c < 6; c++) {
        sx = fmaf(cv[c][nc].x, watt[c], sx);
        sy = fmaf(cv[c][nc].y, watt[c], sy);
      }
      a[nc][0] = sx; a[nc][1] = sy;
    }

    float wb_r[18], wbv_r[18];
    #pragma unroll
    for (int i = 0; i < 18; i++) { wb_r[i] = Wb[i]; wbv_r[i] = Wbv[i]; }
    const float wn0 = (Wpn[0] + Wpn[3] + Wpn[6]) * (1.f / 3.f);
    const float wn1 = (Wpn[1] + Wpn[4] + Wpn[7]) * (1.f / 3.f);
    const float wn2 = (Wpn[2] + Wpn[5] + Wpn[8]) * (1.f / 3.f);
    const float bnb = (bpn[0] + bpn[1] + bpn[2]) * (1.f / 3.f);

    float kk[2][3], vv[2][3], km[3] = {0.f, 0.f, 0.f};
    #pragma unroll
    for (int e = 0; e < 2; e++) {
      float a0 = a[0][e], a1 = a[1][e], a2 = a[2][e];
      float mm = fmaxf(fmaxf(a0, a1), a2);
      float e0 = __expf(a0 - mm), e1 = __expf(a1 - mm), e2 = __expf(a2 - mm);
      float r = 1.f / (e0 + e1 + e2);
      float ga[6];
      #pragma unroll
      for (int c = 0; c < 6; c++) {
        float c0 = e ? cv[c][0].y : cv[c][0].x;
        float c1 = e ? cv[c][1].y : cv[c][1].x;
        float c2 = e ? cv[c][2].y : cv[c][2].x;
        float p0 = e ? pv[c][0].y : pv[c][0].x;
        float p1 = e ? pv[c][1].y : pv[c][1].x;
        float p2 = e ? pv[c][2].y : pv[c][2].x;
        float intra = (c0 * e0 + c1 * e1 + c2 * e2) * r;
        float pn = p0 * wn0 + p1 * wn1 + p2 * wn2 + bnb;
        ga[c] = intra + pn;
      }
      float k0 = 0, k1 = 0, k2 = 0, v0 = 0, v1 = 0, v2 = 0;
      #pragma unroll
      for (int c = 0; c < 6; c++) {
        k0 += wb_r[c] * ga[c];  k1 += wb_r[6 + c] * ga[c];  k2 += wb_r[12 + c] * ga[c];
        v0 += wbv_r[c] * ga[c]; v1 += wbv_r[6 + c] * ga[c]; v2 += wbv_r[12 + c] * ga[c];
      }
      kk[e][0] = k0; kk[e][1] = k1; kk[e][2] = k2;
      vv[e][0] = v0; vv[e][1] = v1; vv[e][2] = v2;
      km[0] = fmaxf(km[0], fabsf(k0));
      km[1] = fmaxf(km[1], fabsf(k1));
      km[2] = fmaxf(km[2], fabsf(k2));
    }

    // ---- K pair layout: key k -> cp=k>>5, c2=(k>>4)&1, pos=k&15
    //      dwords at cp*64 + pos*4 + c2*2 : {pk(k0,k1), pk(k2,0)}
    unsigned* ktg = (unsigned*)ws + KT_U + b * 4096;
    #pragma unroll
    for (int e = 0; e < 2; e++) {
      const int k = l + e;
      const int idxk = (k >> 5) * 64 + (k & 15) * 4 + (((k >> 4) & 1) << 1);
      ktg[idxk]     = h2_bits(__builtin_amdgcn_cvt_pkrtz(kk[e][0], kk[e][1]));
      ktg[idxk + 1] = h2_bits(__builtin_amdgcn_cvt_pkrtz(kk[e][2], 0.f));
    }
    // ---- V pair layout: keys 2pp,2pp+1 share one dword per plane:
    //      dword = cp*64 + plane*16 + (p>>2)*4 + c2*2 + ((p>>1)&1)
    {
      unsigned* vtg = (unsigned*)ws + VT_U + b * 4096;
      const int cp = pp >> 4, c2 = (pp >> 3) & 1, p = (2 * pp) & 15;
      const int base = cp * 64 + (p >> 2) * 4 + c2 * 2 + ((p >> 1) & 1);
      vtg[base]      = h2_bits(__builtin_amdgcn_cvt_pkrtz(vv[0][0], vv[1][0]));
      vtg[base + 16] = h2_bits(__builtin_amdgcn_cvt_pkrtz(vv[0][1], vv[1][1]));
      vtg[base + 32] = h2_bits(__builtin_amdgcn_cvt_pkrtz(vv[0][2], vv[1][2]));
      vtg[base + 48] = h2_bits(__builtin_amdgcn_cvt_pkrtz(1.f, 1.f));
    }

    #pragma unroll
    for (int j = 0; j < 3; j++) km[j] = wave_reduce_max(km[j]);
    if (lane == 0) { for (int j = 0; j < 3; j++) sred[wid * 3 + j] = km[j]; }
    __syncthreads();
    if (tid == 0) {
      for (int j = 0; j < 3; j++)
        ws[PBKM_OFF + (blk - 6) * 3 + j] =
          fmaxf(fmaxf(sred[j], sred[3 + j]), fmaxf(sred[6 + j], sred[9 + j]));
    }
  }
}

// ---------------------------------------------------------------- main ----
// 256 blocks x 1024 thr (16 waves). Block = 256 rows, staged K/V tables
// serve all 16 waves. Wave w: rowgroup rg=w>>2 (64 rows), rp=(w>>1)&1
// (row-tile pair), kh=w&1 (key half: 32 chunk-PAIRS of 32 keys).
// Inner loop per pair: 1 K b128 + 1 V b128 -> 4 score MFMAs + 8x exp2
// -> 4 PV MFMAs (sub-chunk accumulators aX0/aX1).
__global__ __launch_bounds__(1024, 4)
void attn_kernel(const float* __restrict__ x,  const float* __restrict__ Wc,
                 const float* __restrict__ Wd, const float* __restrict__ lng,
                 const float* __restrict__ lnb,
                 const float* __restrict__ Wa, const float* __restrict__ Wav,
                 const float* __restrict__ Wpl, const float* __restrict__ bpl,
                 float* __restrict__ ws, float* __restrict__ yout)
{
  __shared__ __align__(16) unsigned kt[4224];   // 4096 + pad (zeros @4096-4103)
  __shared__ __align__(16) unsigned vt[4224];
  __shared__ float4 cross[4][2][64];            // [rg][kh][row]
  __shared__ float cp[16 * 12];
  __shared__ float gis[18], kis[9], vis[9];
  const int tid  = threadIdx.x, blk = blockIdx.x;
  const int lane = tid & 63, w = tid >> 6;
  const int col  = lane & 15, hi4 = lane >> 4;
  const int rg   = w >> 2, rp = (w >> 1) & 1, kh = w & 1;
  const int rbase = blk * 256;
  const int b    = rbase >> 15;
  const int nb   = rbase & (N_PTS - 1);

  // ---- stage K/V tables (one uint4 per thread each) ----
  {
    const uint4* ktg = (const uint4*)((const unsigned*)ws + KT_U + b * 4096);
    const uint4* vtg = (const uint4*)((const unsigned*)ws + VT_U + b * 4096);
    ((uint4*)kt)[tid] = ktg[tid];
    ((uint4*)vt)[tid] = vtg[tid];
    if (tid < 8) { kt[4096 + tid] = 0; vt[4096 + tid] = 0; }
  }
  if (tid < 18) {
    int c = tid / 3, m = tid % 3;
    float pl_ = bpl[m];
    #pragma unroll
    for (int k = 0; k < 3; k++)
      pl_ = fmaf(Wpl[m * 3 + k], ws[CS_OFF + k * 6 + c] * (1.f / LL), pl_);
    gis[c * 3 + m] = ws[W_OFF + (b * 3 + m) * 6 + c] / ws[MS_OFF + (b * 3 + m) * 2 + 1] + pl_;
  }
  __syncthreads();
  if (tid < 9) {
    int m = tid / 3, k = tid % 3;
    float s1 = 0.f, s2 = 0.f;
    #pragma unroll
    for (int c = 0; c < 6; c++) {
      float g = gis[c * 3 + k];
      s1 = fmaf(Wa [m * 6 + c], g, s1);
      s2 = fmaf(Wav[m * 6 + c], g, s2);
    }
    kis[m * 3 + k] = s1; vis[k * 3 + m] = s2;
  }

  float km0 = 0.f, km1 = 0.f, km2 = 0.f;
  #pragma unroll
  for (int s = 0; s < 4; s++) {
    const float* pk = ws + PBKM_OFF + (b * 4 + s) * 3;
    km0 = fmaxf(km0, pk[0]); km1 = fmaxf(km1, pk[1]); km2 = fmaxf(km2, pk[2]);
  }

  // q for both row-tiles of this wave
  const int nA = nb + rg * 64 + rp * 32 + col, nBr = nA + 16;
  const float* xb = x + (size_t)b * 6 * N_PTS;
  float q0A = 0, q1A = 0, q2A = 0, q0B = 0, q1B = 0, q2B = 0;
  #pragma unroll
  for (int c = 0; c < 6; c++) {
    float xvA = xb[c * N_PTS + nA], xvB = xb[c * N_PTS + nBr];
    q0A = fmaf(xvA, Wc[c], q0A); q1A = fmaf(xvA, Wc[6 + c], q1A); q2A = fmaf(xvA, Wc[12 + c], q2A);
    q0B = fmaf(xvB, Wc[c], q0B); q1B = fmaf(xvB, Wc[6 + c], q1B); q2B = fmaf(xvB, Wc[12 + c], q2B);
  }
  const float KS = 1.4426950408889634f * 0.57735026918962576f;  // log2e/sqrt(3)
  q0A *= KS; q1A *= KS; q2A *= KS; q0B *= KS; q1B *= KS; q2B *= KS;
  const float MpA = fabsf(q0A) * km0 + fabsf(q1A) * km1 + fabsf(q2A) * km2;
  const float MpB = fabsf(q0B) * km0 + fabsf(q1B) * km1 + fabsf(q2B) * km2;

  union U2 { uint2 u; f16x4 h; };
  union U4 { uint4 q; f16x4 h[2]; };
  U2 qbA, qbB;
  qbA.u.x = qbA.u.y = qbB.u.x = qbB.u.y = 0;
  if (hi4 == 0) {
    qbA.u.x = h2_bits(__builtin_amdgcn_cvt_pkrtz(q0A, q1A));
    qbA.u.y = h2_bits(__builtin_amdgcn_cvt_pkrtz(q2A, 0.f));
    qbB.u.x = h2_bits(__builtin_amdgcn_cvt_pkrtz(q0B, q1B));
    qbB.u.y = h2_bits(__builtin_amdgcn_cvt_pkrtz(q2B, 0.f));
  }
  f32x4 cbA = { -MpA, -MpA, -MpA, -MpA };
  f32x4 cbB = { -MpB, -MpB, -MpB, -MpB };
  f32x4 aA0 = {0,0,0,0}, aA1 = {0,0,0,0}, aB0 = {0,0,0,0}, aB1 = {0,0,0,0};

  // pair-layout LDS indices: K lane(col,hi4==0): cp*64 + col*4;
  // V lane(col<4): cp*64 + col*16 + hi4*4. Inactive lanes -> zero pad.
  unsigned ki_ = (hi4 == 0) ? (unsigned)(kh * 2048 + col * 4) : 4096u;
  const unsigned kd = (hi4 == 0) ? 64u : 0u;
  unsigned vi_ = (col < 4) ? (unsigned)(kh * 2048 + col * 16 + hi4 * 4) : 4096u;
  const unsigned vd = (col < 4) ? 64u : 0u;

  __syncthreads();

  U4 Kc, Vc;
  Kc.q = *(const uint4*)&kt[ki_];
  Vc.q = *(const uint4*)&vt[vi_];

  for (int i = 0; i < 32; i++) {      // 32 chunk-pairs = 1024 keys per half
    ki_ += kd; vi_ += vd;
    U4 Kn, Vn;                        // prefetch next pair (last reads pad)
    Kn.q = *(const uint4*)&kt[ki_];
    Vn.q = *(const uint4*)&vt[vi_];

    f32x4 s0A = __builtin_amdgcn_mfma_f32_16x16x16f16(Kc.h[0], qbA.h, cbA, 0, 0, 0);
    f32x4 s0B = __builtin_amdgcn_mfma_f32_16x16x16f16(Kc.h[0], qbB.h, cbB, 0, 0, 0);
    f32x4 s1A = __builtin_amdgcn_mfma_f32_16x16x16f16(Kc.h[1], qbA.h, cbA, 0, 0, 0);
    f32x4 s1B = __builtin_amdgcn_mfma_f32_16x16x16f16(Kc.h[1], qbB.h, cbB, 0, 0, 0);

    U2 PA, PB;
    {
      float e0 = __builtin_amdgcn_exp2f(s0A[0]);
      float e1 = __builtin_amdgcn_exp2f(s0A[1]);
      float e2 = __builtin_amdgcn_exp2f(s0A[2]);
      float e3 = __builtin_amdgcn_exp2f(s0A[3]);
      float f0 = __builtin_amdgcn_exp2f(s0B[0]);
      float f1 = __builtin_amdgcn_exp2f(s0B[1]);
      float f2 = __builtin_amdgcn_exp2f(s0B[2]);
      float f3 = __builtin_amdgcn_exp2f(s0B[3]);
      PA.u.x = h2_bits(__builtin_amdgcn_cvt_pkrtz(e0, e1));
      PA.u.y = h2_bits(__builtin_amdgcn_cvt_pkrtz(e2, e3));
      PB.u.x = h2_bits(__builtin_amdgcn_cvt_pkrtz(f0, f1));
      PB.u.y = h2_bits(__builtin_amdgcn_cvt_pkrtz(f2, f3));
    }
    aA0 = __builtin_amdgcn_mfma_f32_16x16x16f16(Vc.h[0], PA.h, aA0, 0, 0, 0);
    aB0 = __builtin_amdgcn_mfma_f32_16x16x16f16(Vc.h[0], PB.h, aB0, 0, 0, 0);
    {
      float e0 = __builtin_amdgcn_exp2f(s1A[0]);
      float e1 = __builtin_amdgcn_exp2f(s1A[1]);
      float e2 = __builtin_amdgcn_exp2f(s1A[2]);
      float e3 = __builtin_amdgcn_exp2f(s1A[3]);
      float f0 = __builtin_amdgcn_exp2f(s1B[0]);
      float f1 = __builtin_amdgcn_exp2f(s1B[1]);
      float f2 = __builtin_amdgcn_exp2f(s1B[2]);
      float f3 = __builtin_amdgcn_exp2f(s1B[3]);
      PA.u.x = h2_bits(__builtin_amdgcn_cvt_pkrtz(e0, e1));
      PA.u.y = h2_bits(__builtin_amdgcn_cvt_pkrtz(e2, e3));
      PB.u.x = h2_bits(__builtin_amdgcn_cvt_pkrtz(f0, f1));
      PB.u.y = h2_bits(__builtin_amdgcn_cvt_pkrtz(f2, f3));
    }
    aA1 = __builtin_amdgcn_mfma_f32_16x16x16f16(Vc.h[1], PA.h, aA1, 0, 0, 0);
    aB1 = __builtin_amdgcn_mfma_f32_16x16x16f16(Vc.h[1], PB.h, aB1, 0, 0, 0);

    Kc = Kn; Vc = Vn;
  }

  if (hi4 == 0) {
    cross[rg][kh][rp * 32 + col] =
      make_float4(aA0[0] + aA1[0], aA0[1] + aA1[1], aA0[2] + aA1[2], aA0[3] + aA1[3]);
    cross[rg][kh][rp * 32 + 16 + col] =
      make_float4(aB0[0] + aB1[0], aB0[1] + aB1[1], aB0[2] + aB1[2], aB0[3] + aB1[3]);
  }
  __syncthreads();

  float v12[12];
  #pragma unroll
  for (int j = 0; j < 12; j++) v12[j] = 0.f;

  if (tid < 256) {
    const int trg = tid >> 6, ri = tid & 63;
    const int n = nb + trg * 64 + ri;
    float4 c0 = cross[trg][0][ri], c1 = cross[trg][1][ri];
    float w0 = c0.x + c1.x, w1 = c0.y + c1.y, w2 = c0.z + c1.z, dd = c0.w + c1.w;

    float a0 = 0, a1 = 0, a2 = 0;
    #pragma unroll
    for (int c = 0; c < 6; c++) {
      float xv = xb[c * N_PTS + n];
      a0 = fmaf(xv, Wc[c], a0); a1 = fmaf(xv, Wc[6 + c], a1); a2 = fmaf(xv, Wc[12 + c], a2);
    }
    a0 *= KS; a1 *= KS; a2 *= KS;

    float sk0 = a0 * kis[0] + a1 * kis[3] + a2 * kis[6];
    float sk1 = a0 * kis[1] + a1 * kis[4] + a2 * kis[7];
    float sk2 = a0 * kis[2] + a1 * kis[5] + a2 * kis[8];
    float mm  = fmaxf(fmaxf(sk0, sk1), sk2);
    float e0 = __builtin_amdgcn_exp2f(sk0 - mm);
    float e1 = __builtin_amdgcn_exp2f(sk1 - mm);
    float e2 = __builtin_amdgcn_exp2f(sk2 - mm);
    float rs = 1.f / (e0 + e1 + e2);
    float fi0 = (e0 * vis[0] + e1 * vis[3] + e2 * vis[6]) * rs;
    float fi1 = (e0 * vis[1] + e1 * vis[4] + e2 * vis[7]) * rs;
    float fi2 = (e0 * vis[2] + e1 * vis[5] + e2 * vis[8]) * rs;
    float rinv = 1.f / dd;
    float cf[6] = { fi0, fi1, fi2, w0 * rinv, w1 * rinv, w2 * rinv };

    float mu = (cf[0] + cf[1] + cf[2] + cf[3] + cf[4] + cf[5]) * (1.f / 6.f);
    float var = 0.f;
    #pragma unroll
    for (int i = 0; i < 6; i++) { float t = cf[i] - mu; var += t * t; }
    var *= (1.f / 6.f);
    float rn = rsqrtf(var + 1e-5f);
    float cfn[6];
    #pragma unroll
    for (int i = 0; i < 6; i++) cfn[i] = (cf[i] - mu) * rn * lng[i] + lnb[i];

    #pragma unroll
    for (int o = 0; o < 6; o++) {
      float s = 0.f;
      #pragma unroll
      for (int c = 0; c < 6; c++) s += Wd[o * 6 + c] * cfn[c];
      yout[(size_t)b * (6 * N_PTS) + o * N_PTS + n] = s;
      v12[o] = s; v12[6 + o] = s * s;
    }
  }

  // deterministic BN partials (per block)
  #pragma unroll
  for (int j = 0; j < 12; j++) v12[j] = wave_reduce_sum(v12[j]);
  if (lane == 0) { for (int j = 0; j < 12; j++) cp[w * 12 + j] = v12[j]; }
  __syncthreads();
  if (tid == 0) {
    float* part = ws + PART_OFF + blk * 12;
    for (int j = 0; j < 12; j++)
      part[j] = cp[j] + cp[12 + j] + cp[24 + j] + cp[36 + j];
  }
}

// ------------------------------------------------- fused bnstats+final ----
// 384 blocks x 256 thr; each block redundantly reduces the 256x12 partials,
// then applies BN + residual + LeakyReLU to its 1024-element slice.
__global__ __launch_bounds__(256)
void final_kernel(const float* __restrict__ x,
                  const float* __restrict__ bng, const float* __restrict__ bnbt,
                  const float* __restrict__ ws, float* __restrict__ out)
{
  __shared__ float cp[48];
  __shared__ float sc_s[6], sh_s[6];
  const int tid = threadIdx.x, blk = blockIdx.x;
  const int lane = tid & 63, wid = tid >> 6;
  const float* part = ws + PART_OFF;

  float v[12];
  #pragma unroll
  for (int j = 0; j < 12; j++) v[j] = part[tid * 12 + j];
  #pragma unroll
  for (int j = 0; j < 12; j++) v[j] = wave_reduce_sum(v[j]);
  if (lane == 0) { for (int j = 0; j < 12; j++) cp[wid * 12 + j] = v[j]; }
  __syncthreads();
  if (tid < 6) {
    const float inv = 1.f / 65536.f;   // B * N
    float s1 = cp[tid] + cp[12 + tid] + cp[24 + tid] + cp[36 + tid];
    float s2 = cp[6 + tid] + cp[18 + tid] + cp[30 + tid] + cp[42 + tid];
    float mean = s1 * inv;
    float varr = s2 * inv - mean * mean;
    float sc = bng[tid] * rsqrtf(varr + 1e-5f);
    sc_s[tid] = sc;
    sh_s[tid] = bnbt[tid] - mean * sc;
  }
  __syncthreads();

  const int base = blk * 1024 + tid * 4;      // 393216 total
  const int ch = (base >> 15) % 6;
  const float sc = sc_s[ch], sh = sh_s[ch];
  float4 o = *(float4*)&out[base];
  float4 xx = *(const float4*)&x[base];
  float r[4] = { o.x * sc + sh + xx.x, o.y * sc + sh + xx.y,
                 o.z * sc + sh + xx.z, o.w * sc + sh + xx.w };
  #pragma unroll
  for (int j = 0; j < 4; j++) r[j] = r[j] >= 0.f ? r[j] : 0.2f * r[j];
  *(float4*)&out[base] = make_float4(r[0], r[1], r[2], r[3]);
}

// ---------------------------------------------------------------- launch --
extern "C" void kernel_launch(void* const* d_in, const int* in_sizes, int n_in,
                              void* d_out, int out_size, void* d_ws, size_t ws_size,
                              hipStream_t stream)
{
  const float* x      = (const float*)d_in[0];
  const float* curves = (const float*)d_in[1];
  const float* Wa     = (const float*)d_in[2];
  const float* Wav    = (const float*)d_in[3];
  const float* Wb     = (const float*)d_in[4];
  const float* Wbv    = (const float*)d_in[5];
  const float* Wc     = (const float*)d_in[6];
  const float* Wd     = (const float*)d_in[7];
  const float* bng    = (const float*)d_in[8];
  const float* bnbt   = (const float*)d_in[9];
  const float* Watt   = (const float*)d_in[10];
  const float* lng    = (const float*)d_in[11];
  const float* lnbt   = (const float*)d_in[12];
  const float* Wpl    = (const float*)d_in[13];
  const float* bpl    = (const float*)d_in[14];
  const float* Wpn    = (const float*)d_in[15];
  const float* bpn    = (const float*)d_in[16];
  float* out = (float*)d_out;
  float* ws  = (float*)d_ws;

  prep_kernel<<<14, 256, 0, stream>>>(curves, Watt, Wb, Wbv, Wpn, bpn, ws);
  attn_kernel<<<256, 1024, 0, stream>>>(x, Wc, Wd, lng, lnbt,
                                        Wa, Wav, Wpl, bpl, ws, out);
  final_kernel<<<384, 256, 0, stream>>>(x, bng, bnbt, ws, out);
}

// Round 13
// 33.295 us; speedup vs baseline: 1.0918x; 1.0101x over previous
//
#include <hip/hip_runtime.h>
#include <math.h>

#define N_PTS 32768
#define LL    2048

// d_ws dword/float offsets
#define KT_U      0          // uint: [2][4096] K pair-layout table
#define VT_U      8192       // uint: [2][4096] V pair-layout table
#define PART_OFF  16384      // float [1024][12] BN partials
#define MS2_OFF   28672      // [6][8][2]  per-segment {m, expsum}
#define W2_OFF    28768      // [6][8][6]  per-segment exp-weighted sums
#define CS2_OFF   29056      // [3][8][6]  per-segment colsum batch0
#define PBKM_OFF  29200      // [8][3]     per-kvblock |k| max

typedef __fp16 h2    __attribute__((ext_vector_type(2)));
typedef __fp16 f16x4 __attribute__((ext_vector_type(4)));
typedef float  f32x4 __attribute__((ext_vector_type(4)));

__device__ __forceinline__ unsigned h2_bits(h2 h){
  union { h2 h; unsigned u; } x; x.h = h; return x.u;
}
__device__ __forceinline__ float wave_reduce_sum(float v){
  #pragma unroll
  for (int off = 32; off; off >>= 1) v += __shfl_xor(v, off, 64);
  return v;
}
__device__ __forceinline__ float wave_reduce_max(float v){
  #pragma unroll
  for (int off = 32; off; off >>= 1) v = fmaxf(v, __shfl_xor(v, off, 64));
  return v;
}

// ---------------------------------------------------------------- prep ----
// 56 blocks x 256. Blocks 0-47: per-(b,nc,seg) split-softmax partials
// (seg = 256 L-elems). Blocks 48-55: kv table build (pair layout) + |k| max.
__global__ __launch_bounds__(256)
void prep_kernel(const float* __restrict__ curves, const float* __restrict__ Watt,
                 const float* __restrict__ Wb,  const float* __restrict__ Wbv,
                 const float* __restrict__ Wpn, const float* __restrict__ bpn,
                 float* __restrict__ ws)
{
  const int blk = blockIdx.x, tid = threadIdx.x;
  const int lane = tid & 63, wid = tid >> 6;
  __shared__ float sred[4 * 13];
  __shared__ float msh;

  float watt[6];
  #pragma unroll
  for (int c = 0; c < 6; c++) watt[c] = Watt[c];

  if (blk < 48) {
    const int g = blk >> 3, s = blk & 7;     // g = b*3+nc
    const int b = g / 3, nc = g % 3;
    const int l = s * 256 + tid;
    const float* cb = curves + b * 18 * LL;

    float cv[6], av = 0.f;
    #pragma unroll
    for (int c = 0; c < 6; c++) {
      cv[c] = cb[(c * 3 + nc) * LL + l];
      av = fmaf(cv[c], watt[c], av);
    }
    float pm = wave_reduce_max(av);
    if (lane == 0) sred[wid] = pm;
    __syncthreads();
    if (tid == 0) msh = fmaxf(fmaxf(sred[0], sred[1]), fmaxf(sred[2], sred[3]));
    __syncthreads();
    const float m = msh;

    float vals[13];
    float e = __expf(av - m);
    vals[0] = e;
    #pragma unroll
    for (int c = 0; c < 6; c++) {
      vals[1 + c] = cv[c] * e;
      vals[7 + c] = cv[c];
    }
    __syncthreads();
    #pragma unroll
    for (int j = 0; j < 13; j++) vals[j] = wave_reduce_sum(vals[j]);
    if (lane == 0) { for (int j = 0; j < 13; j++) sred[wid * 13 + j] = vals[j]; }
    __syncthreads();
    if (tid == 0) {
      float t[13];
      for (int j = 0; j < 13; j++)
        t[j] = sred[j] + sred[13 + j] + sred[26 + j] + sred[39 + j];
      ws[MS2_OFF + (g * 8 + s) * 2]     = m;
      ws[MS2_OFF + (g * 8 + s) * 2 + 1] = t[0];
      for (int c = 0; c < 6; c++) ws[W2_OFF + (g * 8 + s) * 6 + c] = t[1 + c];
      if (b == 0)
        for (int c = 0; c < 6; c++) ws[CS2_OFF + (nc * 8 + s) * 6 + c] = t[7 + c];
    }
  } else {
    const int idx = (blk - 48) * 256 + tid;  // 0..2047
    const int b = idx >> 10, pp = idx & 1023, l = pp * 2;
    const float* cb = curves + b * 18 * LL;

    float2 cv[6][3], pv[6][3];
    #pragma unroll
    for (int c = 0; c < 6; c++)
      #pragma unroll
      for (int nc = 0; nc < 3; nc++) {
        cv[c][nc] = *(const float2*)&cb[(c * 3 + nc) * LL + l];
        pv[c][nc] = *(const float2*)&curves[(c * 3 + nc) * LL + l];  // batch 0
      }
    float a[3][2];
    #pragma unroll
    for (int nc = 0; nc < 3; nc++) {
      float sx = 0.f, sy = 0.f;
      #pragma unroll
      for (int c = 0; c < 6; c++) {
        sx = fmaf(cv[c][nc].x, watt[c], sx);
        sy = fmaf(cv[c][nc].y, watt[c], sy);
      }
      a[nc][0] = sx; a[nc][1] = sy;
    }

    float wb_r[18], wbv_r[18];
    #pragma unroll
    for (int i = 0; i < 18; i++) { wb_r[i] = Wb[i]; wbv_r[i] = Wbv[i]; }
    const float wn0 = (Wpn[0] + Wpn[3] + Wpn[6]) * (1.f / 3.f);
    const float wn1 = (Wpn[1] + Wpn[4] + Wpn[7]) * (1.f / 3.f);
    const float wn2 = (Wpn[2] + Wpn[5] + Wpn[8]) * (1.f / 3.f);
    const float bnb = (bpn[0] + bpn[1] + bpn[2]) * (1.f / 3.f);

    float kk[2][3], vv[2][3], km[3] = {0.f, 0.f, 0.f};
    #pragma unroll
    for (int e = 0; e < 2; e++) {
      float a0 = a[0][e], a1 = a[1][e], a2 = a[2][e];
      float mm = fmaxf(fmaxf(a0, a1), a2);
      float e0 = __expf(a0 - mm), e1 = __expf(a1 - mm), e2 = __expf(a2 - mm);
      float r = 1.f / (e0 + e1 + e2);
      float ga[6];
      #pragma unroll
      for (int c = 0; c < 6; c++) {
        float c0 = e ? cv[c][0].y : cv[c][0].x;
        float c1 = e ? cv[c][1].y : cv[c][1].x;
        float c2 = e ? cv[c][2].y : cv[c][2].x;
        float p0 = e ? pv[c][0].y : pv[c][0].x;
        float p1 = e ? pv[c][1].y : pv[c][1].x;
        float p2 = e ? pv[c][2].y : pv[c][2].x;
        float intra = (c0 * e0 + c1 * e1 + c2 * e2) * r;
        float pn = p0 * wn0 + p1 * wn1 + p2 * wn2 + bnb;
        ga[c] = intra + pn;
      }
      float k0 = 0, k1 = 0, k2 = 0, v0 = 0, v1 = 0, v2 = 0;
      #pragma unroll
      for (int c = 0; c < 6; c++) {
        k0 += wb_r[c] * ga[c];  k1 += wb_r[6 + c] * ga[c];  k2 += wb_r[12 + c] * ga[c];
        v0 += wbv_r[c] * ga[c]; v1 += wbv_r[6 + c] * ga[c]; v2 += wbv_r[12 + c] * ga[c];
      }
      kk[e][0] = k0; kk[e][1] = k1; kk[e][2] = k2;
      vv[e][0] = v0; vv[e][1] = v1; vv[e][2] = v2;
      km[0] = fmaxf(km[0], fabsf(k0));
      km[1] = fmaxf(km[1], fabsf(k1));
      km[2] = fmaxf(km[2], fabsf(k2));
    }

    // K pair layout: key k -> cp=k>>5, c2=(k>>4)&1, pos=k&15
    unsigned* ktg = (unsigned*)ws + KT_U + b * 4096;
    #pragma unroll
    for (int e = 0; e < 2; e++) {
      const int k = l + e;
      const int idxk = (k >> 5) * 64 + (k & 15) * 4 + (((k >> 4) & 1) << 1);
      ktg[idxk]     = h2_bits(__builtin_amdgcn_cvt_pkrtz(kk[e][0], kk[e][1]));
      ktg[idxk + 1] = h2_bits(__builtin_amdgcn_cvt_pkrtz(kk[e][2], 0.f));
    }
    // V pair layout
    {
      unsigned* vtg = (unsigned*)ws + VT_U + b * 4096;
      const int cp = pp >> 4, c2 = (pp >> 3) & 1, p = (2 * pp) & 15;
      const int base = cp * 64 + (p >> 2) * 4 + c2 * 2 + ((p >> 1) & 1);
      vtg[base]      = h2_bits(__builtin_amdgcn_cvt_pkrtz(vv[0][0], vv[1][0]));
      vtg[base + 16] = h2_bits(__builtin_amdgcn_cvt_pkrtz(vv[0][1], vv[1][1]));
      vtg[base + 32] = h2_bits(__builtin_amdgcn_cvt_pkrtz(vv[0][2], vv[1][2]));
      vtg[base + 48] = h2_bits(__builtin_amdgcn_cvt_pkrtz(1.f, 1.f));
    }

    #pragma unroll
    for (int j = 0; j < 3; j++) km[j] = wave_reduce_max(km[j]);
    if (lane == 0) { for (int j = 0; j < 3; j++) sred[wid * 3 + j] = km[j]; }
    __syncthreads();
    if (tid == 0) {
      for (int j = 0; j < 3; j++)
        ws[PBKM_OFF + (blk - 48) * 3 + j] =
          fmaxf(fmaxf(sred[j], sred[3 + j]), fmaxf(sred[6 + j], sred[9 + j]));
    }
  }
}

// ---------------------------------------------------------------- main ----
// 1024 blocks x 512 thr (8 waves). Block = 64 rows. Wave w: rp=w>>2 (2 row-
// tiles: rows rp*32..rp*32+31), kq=w&3 (key quarter: 16 chunk-pairs).
// launch_bounds(512,8): VGPR cap 64 -> 32 waves/CU (4 blocks x 8 waves,
// LDS ~37KB). Single accumulator per row-tile, no prefetch regs: occupancy
// does the latency hiding.
__global__ __launch_bounds__(512, 8)
void attn_kernel(const float* __restrict__ x,  const float* __restrict__ Wc,
                 const float* __restrict__ Wd, const float* __restrict__ lng,
                 const float* __restrict__ lnb,
                 const float* __restrict__ Wa, const float* __restrict__ Wav,
                 const float* __restrict__ Wpl, const float* __restrict__ bpl,
                 float* __restrict__ ws, float* __restrict__ yout)
{
  __shared__ __align__(16) unsigned kt[4104];   // 4096 + zero pad @4096
  __shared__ __align__(16) unsigned vt[4104];
  __shared__ float4 cross[4][4][16];            // [rowtile][kq][col]
  __shared__ float gis[18], kis[9], vis[9];
  const int tid  = threadIdx.x, blk = blockIdx.x;
  const int lane = tid & 63, w = tid >> 6;
  const int col  = lane & 15, hi4 = lane >> 4;
  const int rp   = w >> 2, kq = w & 3;
  const int rbase = blk * 64;
  const int b    = rbase >> 15;
  const int nb   = rbase & (N_PTS - 1);

  // ---- stage K/V tables ----
  {
    const uint4* ktg = (const uint4*)((const unsigned*)ws + KT_U + b * 4096);
    const uint4* vtg = (const uint4*)((const unsigned*)ws + VT_U + b * 4096);
    uint4* kt4 = (uint4*)kt;
    uint4* vt4 = (uint4*)vt;
    for (int i = tid; i < 1024; i += 512) { kt4[i] = ktg[i]; vt4[i] = vtg[i]; }
    if (tid < 8) { kt[4096 + tid] = 0; vt[4096 + tid] = 0; }
  }
  // gis: combine the 8 split-softmax segments (overlaps staging)
  if (tid < 18) {
    const int c = tid / 3, m = tid % 3;
    const int g = b * 3 + m;
    float mx = -1e30f;
    #pragma unroll
    for (int s = 0; s < 8; s++) mx = fmaxf(mx, ws[MS2_OFF + (g * 8 + s) * 2]);
    float sum = 0.f, Wc_ = 0.f;
    #pragma unroll
    for (int s = 0; s < 8; s++) {
      float e = __expf(ws[MS2_OFF + (g * 8 + s) * 2] - mx);
      sum += ws[MS2_OFF + (g * 8 + s) * 2 + 1] * e;
      Wc_ += ws[W2_OFF + (g * 8 + s) * 6 + c] * e;
    }
    float pl_ = bpl[m];
    #pragma unroll
    for (int k = 0; k < 3; k++) {
      float cs = 0.f;
      #pragma unroll
      for (int s = 0; s < 8; s++) cs += ws[CS2_OFF + (k * 8 + s) * 6 + c];
      pl_ = fmaf(Wpl[m * 3 + k], cs * (1.f / LL), pl_);
    }
    gis[c * 3 + m] = Wc_ / sum + pl_;
  }
  __syncthreads();
  if (tid < 9) {
    int m = tid / 3, k = tid % 3;
    float s1 = 0.f, s2 = 0.f;
    #pragma unroll
    for (int c = 0; c < 6; c++) {
      float g = gis[c * 3 + k];
      s1 = fmaf(Wa [m * 6 + c], g, s1);
      s2 = fmaf(Wav[m * 6 + c], g, s2);
    }
    kis[m * 3 + k] = s1; vis[k * 3 + m] = s2;
  }

  float km0 = 0.f, km1 = 0.f, km2 = 0.f;
  #pragma unroll
  for (int s = 0; s < 4; s++) {
    const float* pk = ws + PBKM_OFF + (b * 4 + s) * 3;
    km0 = fmaxf(km0, pk[0]); km1 = fmaxf(km1, pk[1]); km2 = fmaxf(km2, pk[2]);
  }

  // q for both row-tiles
  const int nA = nb + rp * 32 + col;
  const float* xb = x + (size_t)b * 6 * N_PTS;
  float q0A = 0, q1A = 0, q2A = 0, q0B = 0, q1B = 0, q2B = 0;
  #pragma unroll
  for (int c = 0; c < 6; c++) {
    float xvA = xb[c * N_PTS + nA], xvB = xb[c * N_PTS + nA + 16];
    q0A = fmaf(xvA, Wc[c], q0A); q1A = fmaf(xvA, Wc[6 + c], q1A); q2A = fmaf(xvA, Wc[12 + c], q2A);
    q0B = fmaf(xvB, Wc[c], q0B); q1B = fmaf(xvB, Wc[6 + c], q1B); q2B = fmaf(xvB, Wc[12 + c], q2B);
  }
  const float KS = 1.4426950408889634f * 0.57735026918962576f;  // log2e/sqrt(3)
  q0A *= KS; q1A *= KS; q2A *= KS; q0B *= KS; q1B *= KS; q2B *= KS;
  const float MpA = fabsf(q0A) * km0 + fabsf(q1A) * km1 + fabsf(q2A) * km2;
  const float MpB = fabsf(q0B) * km0 + fabsf(q1B) * km1 + fabsf(q2B) * km2;

  union U2 { uint2 u; f16x4 h; };
  union U4 { uint4 q; f16x4 h[2]; };
  U2 qbA, qbB;
  qbA.u.x = qbA.u.y = qbB.u.x = qbB.u.y = 0;
  if (hi4 == 0) {
    qbA.u.x = h2_bits(__builtin_amdgcn_cvt_pkrtz(q0A, q1A));
    qbA.u.y = h2_bits(__builtin_amdgcn_cvt_pkrtz(q2A, 0.f));
    qbB.u.x = h2_bits(__builtin_amdgcn_cvt_pkrtz(q0B, q1B));
    qbB.u.y = h2_bits(__builtin_amdgcn_cvt_pkrtz(q2B, 0.f));
  }
  f32x4 cbA = { -MpA, -MpA, -MpA, -MpA };
  f32x4 cbB = { -MpB, -MpB, -MpB, -MpB };
  f32x4 aA = {0,0,0,0}, aB = {0,0,0,0};

  unsigned ki_ = (hi4 == 0) ? (unsigned)(kq * 1024 + col * 4) : 4096u;
  const unsigned kd = (hi4 == 0) ? 64u : 0u;
  unsigned vi_ = (col < 4) ? (unsigned)(kq * 1024 + col * 16 + hi4 * 4) : 4096u;
  const unsigned vd = (col < 4) ? 64u : 0u;

  __syncthreads();

  for (int i = 0; i < 16; i++) {      // 16 chunk-pairs = 512 keys per quarter
    U4 K, V;
    K.q = *(const uint4*)&kt[ki_];
    V.q = *(const uint4*)&vt[vi_];
    ki_ += kd; vi_ += vd;

    f32x4 s0A = __builtin_amdgcn_mfma_f32_16x16x16f16(K.h[0], qbA.h, cbA, 0, 0, 0);
    f32x4 s0B = __builtin_amdgcn_mfma_f32_16x16x16f16(K.h[0], qbB.h, cbB, 0, 0, 0);
    f32x4 s1A = __builtin_amdgcn_mfma_f32_16x16x16f16(K.h[1], qbA.h, cbA, 0, 0, 0);
    f32x4 s1B = __builtin_amdgcn_mfma_f32_16x16x16f16(K.h[1], qbB.h, cbB, 0, 0, 0);

    U2 PA, PB;
    {
      float e0 = __builtin_amdgcn_exp2f(s0A[0]);
      float e1 = __builtin_amdgcn_exp2f(s0A[1]);
      float e2 = __builtin_amdgcn_exp2f(s0A[2]);
      float e3 = __builtin_amdgcn_exp2f(s0A[3]);
      float f0 = __builtin_amdgcn_exp2f(s0B[0]);
      float f1 = __builtin_amdgcn_exp2f(s0B[1]);
      float f2 = __builtin_amdgcn_exp2f(s0B[2]);
      float f3 = __builtin_amdgcn_exp2f(s0B[3]);
      PA.u.x = h2_bits(__builtin_amdgcn_cvt_pkrtz(e0, e1));
      PA.u.y = h2_bits(__builtin_amdgcn_cvt_pkrtz(e2, e3));
      PB.u.x = h2_bits(__builtin_amdgcn_cvt_pkrtz(f0, f1));
      PB.u.y = h2_bits(__builtin_amdgcn_cvt_pkrtz(f2, f3));
    }
    aA = __builtin_amdgcn_mfma_f32_16x16x16f16(V.h[0], PA.h, aA, 0, 0, 0);
    aB = __builtin_amdgcn_mfma_f32_16x16x16f16(V.h[0], PB.h, aB, 0, 0, 0);
    {
      float e0 = __builtin_amdgcn_exp2f(s1A[0]);
      float e1 = __builtin_amdgcn_exp2f(s1A[1]);
      float e2 = __builtin_amdgcn_exp2f(s1A[2]);
      float e3 = __builtin_amdgcn_exp2f(s1A[3]);
      float f0 = __builtin_amdgcn_exp2f(s1B[0]);
      float f1 = __builtin_amdgcn_exp2f(s1B[1]);
      float f2 = __builtin_amdgcn_exp2f(s1B[2]);
      float f3 = __builtin_amdgcn_exp2f(s1B[3]);
      PA.u.x = h2_bits(__builtin_amdgcn_cvt_pkrtz(e0, e1));
      PA.u.y = h2_bits(__builtin_amdgcn_cvt_pkrtz(e2, e3));
      PB.u.x = h2_bits(__builtin_amdgcn_cvt_pkrtz(f0, f1));
      PB.u.y = h2_bits(__builtin_amdgcn_cvt_pkrtz(f2, f3));
    }
    aA = __builtin_amdgcn_mfma_f32_16x16x16f16(V.h[1], PA.h, aA, 0, 0, 0);
    aB = __builtin_amdgcn_mfma_f32_16x16x16f16(V.h[1], PB.h, aB, 0, 0, 0);
  }

  if (hi4 == 0) {
    cross[rp * 2][kq][col]     = make_float4(aA[0], aA[1], aA[2], aA[3]);
    cross[rp * 2 + 1][kq][col] = make_float4(aB[0], aB[1], aB[2], aB[3]);
  }
  __syncthreads();

  if (tid < 64) {
    const int rt = tid >> 4, ri = tid & 15;
    const int n = nb + tid;
    float4 c0 = cross[rt][0][ri], c1 = cross[rt][1][ri];
    float4 c2 = cross[rt][2][ri], c3 = cross[rt][3][ri];
    float w0 = c0.x + c1.x + c2.x + c3.x;
    float w1 = c0.y + c1.y + c2.y + c3.y;
    float w2 = c0.z + c1.z + c2.z + c3.z;
    float dd = c0.w + c1.w + c2.w + c3.w;

    float a0 = 0, a1 = 0, a2 = 0;
    #pragma unroll
    for (int c = 0; c < 6; c++) {
      float xv = xb[c * N_PTS + n];
      a0 = fmaf(xv, Wc[c], a0); a1 = fmaf(xv, Wc[6 + c], a1); a2 = fmaf(xv, Wc[12 + c], a2);
    }
    a0 *= KS; a1 *= KS; a2 *= KS;

    float sk0 = a0 * kis[0] + a1 * kis[3] + a2 * kis[6];
    float sk1 = a0 * kis[1] + a1 * kis[4] + a2 * kis[7];
    float sk2 = a0 * kis[2] + a1 * kis[5] + a2 * kis[8];
    float mm  = fmaxf(fmaxf(sk0, sk1), sk2);
    float e0 = __builtin_amdgcn_exp2f(sk0 - mm);
    float e1 = __builtin_amdgcn_exp2f(sk1 - mm);
    float e2 = __builtin_amdgcn_exp2f(sk2 - mm);
    float rs = 1.f / (e0 + e1 + e2);
    float fi0 = (e0 * vis[0] + e1 * vis[3] + e2 * vis[6]) * rs;
    float fi1 = (e0 * vis[1] + e1 * vis[4] + e2 * vis[7]) * rs;
    float fi2 = (e0 * vis[2] + e1 * vis[5] + e2 * vis[8]) * rs;
    float rinv = 1.f / dd;
    float cf[6] = { fi0, fi1, fi2, w0 * rinv, w1 * rinv, w2 * rinv };

    float mu = (cf[0] + cf[1] + cf[2] + cf[3] + cf[4] + cf[5]) * (1.f / 6.f);
    float var = 0.f;
    #pragma unroll
    for (int i = 0; i < 6; i++) { float t = cf[i] - mu; var += t * t; }
    var *= (1.f / 6.f);
    float rn = rsqrtf(var + 1e-5f);
    float cfn[6];
    #pragma unroll
    for (int i = 0; i < 6; i++) cfn[i] = (cf[i] - mu) * rn * lng[i] + lnb[i];

    float v12[12];
    #pragma unroll
    for (int o = 0; o < 6; o++) {
      float s = 0.f;
      #pragma unroll
      for (int c = 0; c < 6; c++) s += Wd[o * 6 + c] * cfn[c];
      yout[(size_t)b * (6 * N_PTS) + o * N_PTS + n] = s;
      v12[o] = s; v12[6 + o] = s * s;
    }
    // deterministic BN partials: all of wave 0 holds 64 distinct rows
    #pragma unroll
    for (int j = 0; j < 12; j++) v12[j] = wave_reduce_sum(v12[j]);
    if (tid == 0) {
      float* part = ws + PART_OFF + blk * 12;
      for (int j = 0; j < 12; j++) part[j] = v12[j];
    }
  }
}

// ------------------------------------------------- fused bnstats+final ----
// 384 blocks x 256 thr; each block redundantly reduces the 1024x12 partials,
// then applies BN + residual + LeakyReLU to its 1024-element slice.
__global__ __launch_bounds__(256)
void final_kernel(const float* __restrict__ x,
                  const float* __restrict__ bng, const float* __restrict__ bnbt,
                  const float* __restrict__ ws, float* __restrict__ out)
{
  __shared__ float cp[48];
  __shared__ float sc_s[6], sh_s[6];
  const int tid = threadIdx.x, blk = blockIdx.x;
  const int lane = tid & 63, wid = tid >> 6;
  const float* part = ws + PART_OFF;

  float v[12];
  #pragma unroll
  for (int j = 0; j < 12; j++) v[j] = 0.f;
  #pragma unroll
  for (int k = 0; k < 4; k++) {
    const float* p = part + (tid * 4 + k) * 12;
    #pragma unroll
    for (int j = 0; j < 12; j++) v[j] += p[j];
  }
  #pragma unroll
  for (int j = 0; j < 12; j++) v[j] = wave_reduce_sum(v[j]);
  if (lane == 0) { for (int j = 0; j < 12; j++) cp[wid * 12 + j] = v[j]; }
  __syncthreads();
  if (tid < 6) {
    const float inv = 1.f / 65536.f;   // B * N
    float s1 = cp[tid] + cp[12 + tid] + cp[24 + tid] + cp[36 + tid];
    float s2 = cp[6 + tid] + cp[18 + tid] + cp[30 + tid] + cp[42 + tid];
    float mean = s1 * inv;
    float varr = s2 * inv - mean * mean;
    float sc = bng[tid] * rsqrtf(varr + 1e-5f);
    sc_s[tid] = sc;
    sh_s[tid] = bnbt[tid] - mean * sc;
  }
  __syncthreads();

  const int base = blk * 1024 + tid * 4;      // 393216 total
  const int ch = (base >> 15) % 6;
  const float sc = sc_s[ch], sh = sh_s[ch];
  float4 o = *(float4*)&out[base];
  float4 xx = *(const float4*)&x[base];
  float r[4] = { o.x * sc + sh + xx.x, o.y * sc + sh + xx.y,
                 o.z * sc + sh + xx.z, o.w * sc + sh + xx.w };
  #pragma unroll
  for (int j = 0; j < 4; j++) r[j] = r[j] >= 0.f ? r[j] : 0.2f * r[j];
  *(float4*)&out[base] = make_float4(r[0], r[1], r[2], r[3]);
}

// ---------------------------------------------------------------- launch --
extern "C" void kernel_launch(void* const* d_in, const int* in_sizes, int n_in,
                              void* d_out, int out_size, void* d_ws, size_t ws_size,
                              hipStream_t stream)
{
  const float* x      = (const float*)d_in[0];
  const float* curves = (const float*)d_in[1];
  const float* Wa     = (const float*)d_in[2];
  const float* Wav    = (const float*)d_in[3];
  const float* Wb     = (const float*)d_in[4];
  const float* Wbv    = (const float*)d_in[5];
  const float* Wc     = (const float*)d_in[6];
  const float* Wd     = (const float*)d_in[7];
  const float* bng    = (const float*)d_in[8];
  const float* bnbt   = (const float*)d_in[9];
  const float* Watt   = (const float*)d_in[10];
  const float* lng    = (const float*)d_in[11];
  const float* lnbt   = (const float*)d_in[12];
  const float* Wpl    = (const float*)d_in[13];
  const float* bpl    = (const float*)d_in[14];
  const float* Wpn    = (const float*)d_in[15];
  const float* bpn    = (const float*)d_in[16];
  float* out = (float*)d_out;
  float* ws  = (float*)d_ws;

  prep_kernel<<<56, 256, 0, stream>>>(curves, Watt, Wb, Wbv, Wpn, bpn, ws);
  attn_kernel<<<1024, 512, 0, stream>>>(x, Wc, Wd, lng, lnbt,
                                        Wa, Wav, Wpl, bpl, ws, out);
  final_kernel<<<384, 256, 0, stream>>>(x, bng, bnbt, ws, out);
}